// Round 13
// baseline (376.530 us; speedup 1.0000x reference)
//
#include <hip/hip_runtime.h>
#include <hip/hip_bf16.h>
#include <stdint.h>

// HiPPO-LegT LTI scan: c_t = dA c_{t-1} + dB u_t, out = all c_t. N=256, L=4096, B=64.
//   c[k*64+dt] = dA^{dt+1} . s_k  +  sum_{p<=dt} (dA^p dB) . u[k*64+dt-p]   (main_gemm, MFMA)
//   s_k via Kogge-Stone over chunk finals (6 MFMA GEMM levels, 64x64 tiles, full chip).
// All fp32 data; MFMA operands split bf16 hi/lo (3-MFMA products, rel err ~2^-17).
// POST-MORTEMS baked in:
//  r4: LDS XOR-swizzle in main_gemm regressed -> keep linear-row layout.
//  r5: cooperative grid.sync fusion = 983us barrier spin -> multi-launch only.
//  r6: 2-dt main_gemm spilled (2.1GB scratch traffic) -> single-dt kept.
//  r7: sq_mm folded as rider blocks into finals/ks launches (worked; kept).
//  r8: register prefetch in mm64_tile/ks_tile + K-doubling riders (worked; kept).
//  r9: carry-phase register prefetch one kt ahead (worked; 177->165us).
//  r10: stride 40->36: conflicts halved, dur flat -> capacity/conflicts not binding.
//  r11: A-from-global regressed (latency-exposed dependent loads) -> reverted.
//  r12: single-barrier dbuf regressed (LDS 72KB -> 2 blocks/CU, occ 21%) -> reverted.
//  r13: XCD-aware block swizzle in main_gemm: each dt's 64 blocks map to ONE XCD,
//       contiguous in dispatch (dt = xcd + 8*(l>>6)) -> P[dt] slice stays L2-resident.
//       Workload balanced: each XCD gets 4 small-dt + 4 large-dt groups.

#define N 256
#define LSEQ 4096
#define BATCH 64
#define TCH 64
#define NCH 64

#define MG_STRIDE 36   // main_gemm LDS row stride in shorts

using bf16x8 = __attribute__((ext_vector_type(8))) __bf16;
using f32x4  = __attribute__((ext_vector_type(4))) float;

__device__ __forceinline__ unsigned short f2bf(float f) {
  uint32_t x = __builtin_bit_cast(uint32_t, f);
  uint32_t r = x + 0x7fffu + ((x >> 16) & 1u);
  return (unsigned short)(r >> 16);
}
__device__ __forceinline__ float bf2f(unsigned short h) {
  uint32_t x = ((uint32_t)h) << 16;
  return __builtin_bit_cast(float, x);
}

__device__ __forceinline__ int swz(int r, int c) { return r * 32 + ((c ^ ((r >> 1) & 3)) << 3); }

// ws offsets (bytes)
#define OFF_Phi 16777216
#define OFF_Plo 25165824
#define OFF_Kf  33554432
#define OFF_Khi 33619968
#define OFF_Klo 33652736
#define OFF_shi 33685504
#define OFF_slo 35782656
#define OFF_G0  37879808
#define OFF_uT  42074112
#define OFF_Sqh 43122688
#define OFF_Sql 43778048

// ---------- device phase bodies ----------

// 64x64 fp32 GEMM tile with k0-prefetch: C = A @ B, fp32 C + bf16 hi/lo split.
__device__ __forceinline__ void mm64_tile(const float* __restrict__ A, const float* __restrict__ B,
                                          float* __restrict__ Cw, unsigned short* __restrict__ Chi,
                                          unsigned short* __restrict__ Clo, int bx, int tid,
                                          char* smem) {
  float (*At)[68] = (float(*)[68])smem;
  float (*Bs)[68] = (float(*)[68])(smem + 4352);
  int gr0 = (bx >> 2) * 64, gc0 = (bx & 3) * 64;
  int ty = tid >> 4, tx = tid & 15;
  float acc[4][4];
  #pragma unroll
  for (int r = 0; r < 4; ++r)
    #pragma unroll
    for (int c = 0; c < 4; ++c) acc[r][c] = 0.f;
  int ra = tid >> 2, ka4 = (tid & 3) << 2;
  int kb = tid >> 4, cb4 = (tid & 15) << 2;
  const float* pa = &A[(size_t)(gr0 + ra) * 256 + ka4];
  const float* pb = &B[(size_t)kb * 256 + gc0 + cb4];
  float4 va = *(const float4*)pa;
  float4 vb = *(const float4*)pb;
  for (int k0 = 0; k0 < 256; k0 += 16) {
    At[ka4 + 0][ra] = va.x; At[ka4 + 1][ra] = va.y;
    At[ka4 + 2][ra] = va.z; At[ka4 + 3][ra] = va.w;
    *(float4*)&Bs[kb][cb4] = vb;
    __syncthreads();
    if (k0 + 16 < 256) {
      va = *(const float4*)(pa + k0 + 16);
      vb = *(const float4*)(pb + (size_t)(k0 + 16) * 256);
    }
    #pragma unroll
    for (int kk = 0; kk < 16; ++kk) {
      float4 a4 = *(const float4*)&At[kk][ty << 2];
      float4 b4 = *(const float4*)&Bs[kk][tx << 2];
      acc[0][0] += a4.x * b4.x; acc[0][1] += a4.x * b4.y; acc[0][2] += a4.x * b4.z; acc[0][3] += a4.x * b4.w;
      acc[1][0] += a4.y * b4.x; acc[1][1] += a4.y * b4.y; acc[1][2] += a4.y * b4.z; acc[1][3] += a4.y * b4.w;
      acc[2][0] += a4.z * b4.x; acc[2][1] += a4.z * b4.y; acc[2][2] += a4.z * b4.z; acc[2][3] += a4.z * b4.w;
      acc[3][0] += a4.w * b4.x; acc[3][1] += a4.w * b4.y; acc[3][2] += a4.w * b4.z; acc[3][3] += a4.w * b4.w;
    }
    __syncthreads();
  }
  #pragma unroll
  for (int r = 0; r < 4; ++r)
    #pragma unroll
    for (int c = 0; c < 4; ++c) {
      size_t idx = (size_t)(gr0 + ty * 4 + r) * 256 + gc0 + tx * 4 + c;
      float v = acc[r][c];
      Cw[idx] = v;
      unsigned short h = f2bf(v);
      Chi[idx] = h;
      Clo[idx] = f2bf(v - bf2f(h));
    }
}

__device__ __forceinline__ void finals_one(const float* __restrict__ Kf, const float* __restrict__ u,
                                           float* __restrict__ G0, int k, int b, int i) {
  float acc = 0.f;
  int ubase = (k * TCH + 63) * BATCH + b;
  #pragma unroll 8
  for (int p = 0; p < TCH; ++p)
    acc += Kf[p * N + i] * u[ubase - p * BATCH];
  G0[(size_t)(k * BATCH + b) * N + i] = acc;
}

// one Kogge-Stone 64x64 tile with kt-prefetch: Gout[m] = Gin[m] + Gin[m-shift] @ M^T.
template <int FINAL>
__device__ __forceinline__ void ks_tile(int bx, int tid, const float* __restrict__ Gin,
                                        float* __restrict__ Gout,
                                        const unsigned short* __restrict__ Mh,
                                        const unsigned short* __restrict__ Ml, int shift,
                                        unsigned short* __restrict__ shi,
                                        unsigned short* __restrict__ slo, char* smem) {
  unsigned short* Ah = (unsigned short*)smem;
  unsigned short* Al = (unsigned short*)(smem + 4096);
  unsigned short* Bh = (unsigned short*)(smem + 8192);
  unsigned short* Bl = (unsigned short*)(smem + 12288);
  int kb0 = (bx >> 2) * 64, i0 = (bx & 3) * 64;
  int lane = tid & 63, wid = tid >> 6;
  int wr = wid >> 1, wc = wid & 1;
  int rg = lane >> 4, cl = lane & 15;

  f32x4 acc[2][2];
  #pragma unroll
  for (int mf = 0; mf < 2; ++mf) {
    int m0 = kb0 + wr * 32 + mf * 16 + rg * 4;
    #pragma unroll
    for (int nf = 0; nf < 2; ++nf) {
      int i = i0 + wc * 32 + nf * 16 + cl;
      #pragma unroll
      for (int r = 0; r < 4; ++r)
        acc[mf][nf][r] = Gin[(size_t)(m0 + r) * 256 + i];
    }
  }

  int sr = tid >> 2, kc = tid & 3;
  int sw = swz(sr, kc);
  int srow = kb0 + sr - shift;
  bool haveA = (srow >= 0);
  const float* srcA = &Gin[(size_t)(haveA ? srow : 0) * 256 + kc * 8];
  const unsigned short* srcBh = &Mh[(size_t)(i0 + sr) * 256 + kc * 8];
  const unsigned short* srcBl = &Ml[(size_t)(i0 + sr) * 256 + kc * 8];

  float4 rA0, rA1;
  uint4 rBh = *(const uint4*)srcBh, rBl = *(const uint4*)srcBl;
  if (haveA) { rA0 = *(const float4*)srcA; rA1 = *(const float4*)(srcA + 4); }

  for (int kt = 0; kt < 8; ++kt) {
    if (haveA) {
      float vv[8] = {rA0.x, rA0.y, rA0.z, rA0.w, rA1.x, rA1.y, rA1.z, rA1.w};
      unsigned short hv[8], lv[8];
      #pragma unroll
      for (int e = 0; e < 8; ++e) {
        hv[e] = f2bf(vv[e]);
        lv[e] = f2bf(vv[e] - bf2f(hv[e]));
      }
      *(uint4*)&Ah[sw] = *(const uint4*)hv;
      *(uint4*)&Al[sw] = *(const uint4*)lv;
    } else {
      uint4 z = {0, 0, 0, 0};
      *(uint4*)&Ah[sw] = z;
      *(uint4*)&Al[sw] = z;
    }
    *(uint4*)&Bh[sw] = rBh;
    *(uint4*)&Bl[sw] = rBl;
    __syncthreads();

    if (kt < 7) {
      int off = (kt + 1) * 32;
      if (haveA) { rA0 = *(const float4*)(srcA + off); rA1 = *(const float4*)(srcA + off + 4); }
      rBh = *(const uint4*)(srcBh + off);
      rBl = *(const uint4*)(srcBl + off);
    }

    int fr = lane & 15, kseg = lane >> 4;
    bf16x8 ah[2], al[2], bh[2], bl[2];
    #pragma unroll
    for (int mf = 0; mf < 2; ++mf) {
      int row = wr * 32 + mf * 16 + fr;
      ah[mf] = *(const bf16x8*)&Ah[swz(row, kseg)];
      al[mf] = *(const bf16x8*)&Al[swz(row, kseg)];
    }
    #pragma unroll
    for (int nf = 0; nf < 2; ++nf) {
      int row = wc * 32 + nf * 16 + fr;
      bh[nf] = *(const bf16x8*)&Bh[swz(row, kseg)];
      bl[nf] = *(const bf16x8*)&Bl[swz(row, kseg)];
    }
    #pragma unroll
    for (int mf = 0; mf < 2; ++mf)
      #pragma unroll
      for (int nf = 0; nf < 2; ++nf) {
        acc[mf][nf] = __builtin_amdgcn_mfma_f32_16x16x32_bf16(ah[mf], bh[nf], acc[mf][nf], 0, 0, 0);
        acc[mf][nf] = __builtin_amdgcn_mfma_f32_16x16x32_bf16(ah[mf], bl[nf], acc[mf][nf], 0, 0, 0);
        acc[mf][nf] = __builtin_amdgcn_mfma_f32_16x16x32_bf16(al[mf], bh[nf], acc[mf][nf], 0, 0, 0);
      }
    __syncthreads();
  }

  #pragma unroll
  for (int mf = 0; mf < 2; ++mf) {
    int m0 = kb0 + wr * 32 + mf * 16 + rg * 4;
    #pragma unroll
    for (int nf = 0; nf < 2; ++nf) {
      int i = i0 + wc * 32 + nf * 16 + cl;
      #pragma unroll
      for (int r = 0; r < 4; ++r) {
        if (FINAL) {
          int tm = m0 + r + 64;
          if (tm < 4096) {
            float v = acc[mf][nf][r];
            unsigned short h = f2bf(v);
            shi[(size_t)tm * 256 + i] = h;
            slo[(size_t)tm * 256 + i] = f2bf(v - bf2f(h));
          }
        } else {
          Gout[(size_t)(m0 + r) * 256 + i] = acc[mf][nf][r];
        }
      }
    }
  }
  if (FINAL && kb0 == 0) {
    for (int e = tid; e < 4096; e += 256) {
      size_t o = (size_t)(e >> 6) * 256 + i0 + (e & 63);
      shi[o] = 0;
      slo[o] = 0;
    }
  }
}

// ---------- standalone kernels ----------

// prep0: bid<64 transpose u; bid<128 dA copy/split; bid==128 K[0]=dB init.
__global__ __launch_bounds__(256) void prep0(const float* __restrict__ u, const float* __restrict__ dA,
                                             const float* __restrict__ dB,
                                             float* __restrict__ uT, float* __restrict__ Pw,
                                             unsigned short* __restrict__ Phi, unsigned short* __restrict__ Plo,
                                             float* __restrict__ Kf, unsigned short* __restrict__ Khi,
                                             unsigned short* __restrict__ Klo) {
  __shared__ float tile[64][65];
  int bid = blockIdx.x, tid = threadIdx.x;
  if (bid < 64) {
    int t0 = bid * 64;
    #pragma unroll
    for (int q = 0; q < 16; ++q) {
      int e = q * 256 + tid;
      int tt = e >> 6, b = e & 63;
      tile[b][tt] = u[(size_t)(t0 + tt) * 64 + b];
    }
    __syncthreads();
    #pragma unroll
    for (int q = 0; q < 16; ++q) {
      int e = q * 256 + tid;
      int b = e >> 6, tt = e & 63;
      uT[(size_t)b * 4096 + t0 + tt] = tile[b][tt];
    }
  } else if (bid < 128) {
    int base = (bid - 64) * 1024 + tid * 4;
    float4 v = *(const float4*)&dA[base];
    *(float4*)&Pw[base] = v;
    float vv[4] = {v.x, v.y, v.z, v.w};
    #pragma unroll
    for (int q = 0; q < 4; ++q) {
      unsigned short h = f2bf(vv[q]);
      Phi[base + q] = h;
      Plo[base + q] = f2bf(vv[q] - bf2f(h));
    }
  } else {
    float v = dB[tid];
    Kf[tid] = v;
    unsigned short h = f2bf(v);
    Khi[tid] = h;
    Klo[tid] = f2bf(v - bf2f(h));
  }
}

// pow_K: level half. Blocks [0,16*half): P[half+q] = P[q] @ P[half] (fp32 + split).
// Blocks [16*half, 20*half): K-riders, K[half+j] = P[half] . K[j] (wave row-dots).
__global__ __launch_bounds__(256) void pow_K(float* __restrict__ Pw,
                                             unsigned short* __restrict__ Phi,
                                             unsigned short* __restrict__ Plo,
                                             float* __restrict__ Kf,
                                             unsigned short* __restrict__ Khi,
                                             unsigned short* __restrict__ Klo,
                                             int half) {
  __shared__ __align__(16) char smem[16640];
  int bx = blockIdx.x, tid = threadIdx.x;
  if (bx < 16 * half) {
    int q = (bx >> 4) + 1, t = bx & 15;
    mm64_tile(Pw + (size_t)(q - 1) * 65536, Pw + (size_t)(half - 1) * 65536,
              Pw + (size_t)(half + q - 1) * 65536, Phi + (size_t)(half + q - 1) * 65536,
              Plo + (size_t)(half + q - 1) * 65536, t, tid, smem);
  } else {
    int r = bx - 16 * half;
    int jp = r >> 2, quarter = r & 3;
    int p = half + jp;
    const float* M = Pw + (size_t)(half - 1) * 65536;
    const float* v = Kf + (size_t)jp * 256;
    int lane = tid & 63, w = tid >> 6;
    float d0 = v[lane], d1 = v[lane + 64], d2 = v[lane + 128], d3 = v[lane + 192];
    for (int ii = 0; ii < 16; ++ii) {
      int i = quarter * 64 + w * 16 + ii;
      const float* row = M + (size_t)i * 256;
      float acc = row[lane] * d0 + row[lane + 64] * d1 + row[lane + 128] * d2 + row[lane + 192] * d3;
      #pragma unroll
      for (int off = 32; off; off >>= 1) acc += __shfl_xor(acc, off, 64);
      if (lane == 0) {
        Kf[p * 256 + i] = acc;
        unsigned short h = f2bf(acc);
        Khi[p * 256 + i] = h;
        Klo[p * 256 + i] = f2bf(acc - bf2f(h));
      }
    }
  }
}

// finals (grid 65 x 64) + folded sq0.
__global__ __launch_bounds__(256) void finals_sq(const float* __restrict__ Kf, const float* __restrict__ u,
                                                 float* __restrict__ G0,
                                                 const float* __restrict__ S0, float* __restrict__ S1,
                                                 unsigned short* __restrict__ Sqh0,
                                                 unsigned short* __restrict__ Sql0) {
  __shared__ __align__(16) char smem[16640];
  if (blockIdx.x < 64) {
    finals_one(Kf, u, G0, blockIdx.x, blockIdx.y, threadIdx.x);
  } else if (blockIdx.y < 16) {
    mm64_tile(S0, S0, S1, Sqh0, Sql0, blockIdx.y, threadIdx.x, smem);
  }
}

// ks_level + optional folded square: blocks >=256 compute SqC = SqA @ SqA (16 tiles).
template <int FINAL>
__global__ __launch_bounds__(256) void ks_level(const float* __restrict__ Gin, float* __restrict__ Gout,
                                                const unsigned short* __restrict__ Mh,
                                                const unsigned short* __restrict__ Ml, int shift,
                                                unsigned short* __restrict__ shi,
                                                unsigned short* __restrict__ slo,
                                                const float* __restrict__ SqA, float* __restrict__ SqC,
                                                unsigned short* __restrict__ SqChi,
                                                unsigned short* __restrict__ SqClo) {
  __shared__ __align__(16) char smem[16640];
  int bx = blockIdx.x;
  if (bx < 256) {
    ks_tile<FINAL>(bx, threadIdx.x, Gin, Gout, Mh, Ml, shift, shi, slo, smem);
  } else {
    mm64_tile(SqA, SqA, SqC, SqChi, SqClo, bx - 256, threadIdx.x, smem);
  }
}

// main_gemm: out[k*64+dt][b][i] = sum_j P[dt+1][i][j] s_k[b][j] + sum_{p<=dt} K[p][i] u[kT+dt-p][b]
// r10 structure (stride-36, reg-prefetch, 2-barrier) + r13 XCD-aware block swizzle:
// flat dispatch index f -> xcd = f&7 (HW round-robin), local l = f>>3;
// dt = xcd + 8*(l>>6) (each dt entirely on one XCD, temporally contiguous),
// xk = l&63 -> (it, kbt). Bijection over (dt, xk); balanced 9/10-kt mix per XCD.
__global__ __launch_bounds__(256, 2) void main_gemm(const unsigned short* __restrict__ shi,
                                                    const unsigned short* __restrict__ slo,
                                                    const unsigned short* __restrict__ Phi,
                                                    const unsigned short* __restrict__ Plo,
                                                    const unsigned short* __restrict__ Khi,
                                                    const unsigned short* __restrict__ Klo,
                                                    const float* __restrict__ uT,
                                                    float* __restrict__ out) {
  __shared__ unsigned short Ah[128 * MG_STRIDE], Al[128 * MG_STRIDE];
  __shared__ unsigned short Bh[128 * MG_STRIDE], Bl[128 * MG_STRIDE];
  int flat = blockIdx.y * 64 + blockIdx.x;
  int xcd = flat & 7;
  int l = flat >> 3;
  int dt = xcd + ((l >> 6) << 3);
  int xk = l & 63;
  int it = xk >> 5, kbt = xk & 31;
  int kb0 = kbt * 128, i0 = it * 128;
  int tid = threadIdx.x;
  int lane = tid & 63, wid = tid >> 6;
  int wr = wid >> 1, wc = wid & 1;

  f32x4 acc[4][4];
  #pragma unroll
  for (int mf = 0; mf < 4; ++mf)
    #pragma unroll
    for (int nf = 0; nf < 4; ++nf)
      #pragma unroll
      for (int r = 0; r < 4; ++r) acc[mf][nf][r] = 0.f;

  const unsigned short* PhiD = Phi + (size_t)dt * 65536;
  const unsigned short* PloD = Plo + (size_t)dt * 65536;
  int nkt = (dt >= 32) ? 10 : 9;

  // carry-phase staging bases (loop-invariant); prefetch regs hold kt's 8 uint4
  int r = tid >> 1, h = tid & 1;
  int lo_ = r * MG_STRIDE + h * 16;
  const unsigned short* b1 = shi  + (size_t)(kb0 + r) * 256 + h * 16;
  const unsigned short* b2 = slo  + (size_t)(kb0 + r) * 256 + h * 16;
  const unsigned short* b3 = PhiD + (size_t)(i0 + r) * 256 + h * 16;
  const unsigned short* b4 = PloD + (size_t)(i0 + r) * 256 + h * 16;
  uint4 r1a = *(const uint4*)b1;
  uint4 r1b = *(const uint4*)(b1 + 8);
  uint4 r2a = *(const uint4*)b2;
  uint4 r2b = *(const uint4*)(b2 + 8);
  uint4 r3a = *(const uint4*)b3;
  uint4 r3b = *(const uint4*)(b3 + 8);
  uint4 r4a = *(const uint4*)b4;
  uint4 r4b = *(const uint4*)(b4 + 8);

  for (int kt = 0; kt < nkt; ++kt) {
    if (kt < 8) {
      *(uint4*)&Ah[lo_]     = r1a;
      *(uint4*)&Ah[lo_ + 8] = r1b;
      *(uint4*)&Al[lo_]     = r2a;
      *(uint4*)&Al[lo_ + 8] = r2b;
      *(uint4*)&Bh[lo_]     = r3a;
      *(uint4*)&Bh[lo_ + 8] = r3b;
      *(uint4*)&Bl[lo_]     = r4a;
      *(uint4*)&Bl[lo_ + 8] = r4b;
    } else {
      int p0 = (kt - 8) * 32;
      int kk = (kb0 + r) >> 6, b = (kb0 + r) & 63;
      const float* ub2 = uT + (size_t)b * 4096 + kk * 64 + dt;
      #pragma unroll
      for (int qq = 0; qq < 16; ++qq) {
        int pp = h * 16 + qq;
        int sh = p0 + pp;
        float v = (sh <= dt) ? ub2[-sh] : 0.f;
        unsigned short hv = f2bf(v);
        Ah[r * MG_STRIDE + pp] = hv;
        Al[r * MG_STRIDE + pp] = f2bf(v - bf2f(hv));
      }
      int n = tid & 127, ph = tid >> 7;
      #pragma unroll
      for (int qq = 0; qq < 16; ++qq) {
        int pp = ph * 16 + qq;
        Bh[n * MG_STRIDE + pp] = Khi[(p0 + pp) * 256 + i0 + n];
        Bl[n * MG_STRIDE + pp] = Klo[(p0 + pp) * 256 + i0 + n];
      }
    }
    __syncthreads();

    // issue next carry-phase loads early: latency hides under this kt's MFMAs
    if (kt + 1 < 8) {
      int co = (kt + 1) * 32;
      r1a = *(const uint4*)(b1 + co);
      r1b = *(const uint4*)(b1 + co + 8);
      r2a = *(const uint4*)(b2 + co);
      r2b = *(const uint4*)(b2 + co + 8);
      r3a = *(const uint4*)(b3 + co);
      r3b = *(const uint4*)(b3 + co + 8);
      r4a = *(const uint4*)(b4 + co);
      r4b = *(const uint4*)(b4 + co + 8);
    }

    int kseg = lane >> 4, fr = lane & 15;
    bf16x8 ah[4], al[4], bh[4], bl[4];
    #pragma unroll
    for (int mf = 0; mf < 4; ++mf) {
      int row = (wr * 64 + mf * 16 + fr) * MG_STRIDE + kseg * 8;
      ah[mf] = *(const bf16x8*)&Ah[row];
      al[mf] = *(const bf16x8*)&Al[row];
    }
    #pragma unroll
    for (int nf = 0; nf < 4; ++nf) {
      int row = (wc * 64 + nf * 16 + fr) * MG_STRIDE + kseg * 8;
      bh[nf] = *(const bf16x8*)&Bh[row];
      bl[nf] = *(const bf16x8*)&Bl[row];
    }
    #pragma unroll
    for (int mf = 0; mf < 4; ++mf)
      #pragma unroll
      for (int nf = 0; nf < 4; ++nf) {
        acc[mf][nf] = __builtin_amdgcn_mfma_f32_16x16x32_bf16(ah[mf], bh[nf], acc[mf][nf], 0, 0, 0);
        acc[mf][nf] = __builtin_amdgcn_mfma_f32_16x16x32_bf16(ah[mf], bl[nf], acc[mf][nf], 0, 0, 0);
        acc[mf][nf] = __builtin_amdgcn_mfma_f32_16x16x32_bf16(al[mf], bh[nf], acc[mf][nf], 0, 0, 0);
      }
    __syncthreads();
  }

  int rg = lane >> 4, cl = lane & 15;
  #pragma unroll
  for (int mf = 0; mf < 4; ++mf) {
    int kbrow_base = kb0 + wr * 64 + mf * 16 + rg * 4;
    #pragma unroll
    for (int nf = 0; nf < 4; ++nf) {
      int i = i0 + wc * 64 + nf * 16 + cl;
      #pragma unroll
      for (int rr = 0; rr < 4; ++rr) {
        int kbrow = kbrow_base + rr;
        int k = kbrow >> 6, b = kbrow & 63;
        size_t t = (size_t)(k * 64 + dt);
        out[(t * 64 + b) * 256 + i] = acc[mf][nf][rr];
      }
    }
  }
}

// ======================= HOST =======================

extern "C" void kernel_launch(void* const* d_in, const int* in_sizes, int n_in,
                              void* d_out, int out_size, void* d_ws, size_t ws_size,
                              hipStream_t stream) {
  (void)in_sizes; (void)n_in; (void)out_size;
  const float* u  = (const float*)d_in[0];
  const float* dA = (const float*)d_in[1];
  const float* dB = (const float*)d_in[2];
  float* out = (float*)d_out;
  char* ws = (char*)d_ws;

  float*          Pw  = (float*)(ws);
  unsigned short* Phi = (unsigned short*)(ws + OFF_Phi);
  unsigned short* Plo = (unsigned short*)(ws + OFF_Plo);
  float*          Kf  = (float*)(ws + OFF_Kf);
  unsigned short* Khi = (unsigned short*)(ws + OFF_Khi);
  unsigned short* Klo = (unsigned short*)(ws + OFF_Klo);
  unsigned short* shi = (unsigned short*)(ws + OFF_shi);
  unsigned short* slo = (unsigned short*)(ws + OFF_slo);
  float*          G0  = (float*)(ws + OFF_G0);
  unsigned short* Sqh = (unsigned short*)(ws + OFF_Sqh);
  unsigned short* Sql = (unsigned short*)(ws + OFF_Sql);

  const size_t NEED_KS = 44433408;
  if (ws_size < NEED_KS) return;  // proven available in prior rounds

  float* G1 = (float*)ws;  // aliases Pw slots 0..15 (dead once K built)

  // fp32 squares: S[0]=dA^64 (Pw slot 63); S[1..5] in Pw slots 56..60
  float* S[6];
  S[0] = Pw + (size_t)63 * 65536;
  for (int d = 1; d <= 5; ++d) S[d] = Pw + (size_t)(55 + d) * 65536;

  prep0<<<129, 256, 0, stream>>>(u, dA, dB, (float*)(ws + OFF_uT), Pw, Phi, Plo, Kf, Khi, Klo);
  for (int half = 1; half <= 32; half <<= 1)
    pow_K<<<20 * half, 256, 0, stream>>>(Pw, Phi, Plo, Kf, Khi, Klo, half);

  // finals + sq0 (M^2) folded
  finals_sq<<<dim3(65, 64), 256, 0, stream>>>(Kf, u, G0, S[0], S[1], Sqh, Sql);

  const unsigned short* Mh0 = Phi + (size_t)63 * 65536;
  const unsigned short* Ml0 = Plo + (size_t)63 * 65536;
  // ks L0 (+sq1: M^4), L1 (+sq2: M^8), L2 (+sq3: M^16), L3 (+sq4: M^32), L4, L5(final)
  ks_level<0><<<272, 256, 0, stream>>>(G0, G1, Mh0, Ml0, 64, nullptr, nullptr,
                                       S[1], S[2], Sqh + 1 * 65536, Sql + 1 * 65536);
  ks_level<0><<<272, 256, 0, stream>>>(G1, G0, Sqh + 0 * 65536, Sql + 0 * 65536, 128, nullptr, nullptr,
                                       S[2], S[3], Sqh + 2 * 65536, Sql + 2 * 65536);
  ks_level<0><<<272, 256, 0, stream>>>(G0, G1, Sqh + 1 * 65536, Sql + 1 * 65536, 256, nullptr, nullptr,
                                       S[3], S[4], Sqh + 3 * 65536, Sql + 3 * 65536);
  ks_level<0><<<272, 256, 0, stream>>>(G1, G0, Sqh + 2 * 65536, Sql + 2 * 65536, 512, nullptr, nullptr,
                                       S[4], S[5], Sqh + 4 * 65536, Sql + 4 * 65536);
  ks_level<0><<<256, 256, 0, stream>>>(G0, G1, Sqh + 3 * 65536, Sql + 3 * 65536, 1024, nullptr, nullptr,
                                       nullptr, nullptr, nullptr, nullptr);
  ks_level<1><<<256, 256, 0, stream>>>(G1, nullptr, Sqh + 4 * 65536, Sql + 4 * 65536, 2048, shi, slo,
                                       nullptr, nullptr, nullptr, nullptr);

  main_gemm<<<dim3(64, 64), 256, 0, stream>>>(shi, slo, Phi, Plo, Khi, Klo,
                                              (const float*)(ws + OFF_uT), out);
}

// Round 14
// 348.053 us; speedup vs baseline: 1.0818x; 1.0818x over previous
//
#include <hip/hip_runtime.h>
#include <hip/hip_bf16.h>
#include <stdint.h>

// HiPPO-LegT LTI scan: c_t = dA c_{t-1} + dB u_t, out = all c_t. N=256, L=4096, B=64.
//   c[k*64+dt] = dA^{dt+1} . s_k  +  sum_{p<=dt} (dA^p dB) . u[k*64+dt-p]   (main_gemm, MFMA)
//   s_k via Kogge-Stone over chunk finals (6 MFMA GEMM levels, 64x64 tiles, full chip).
// All fp32 data; MFMA operands split bf16 hi/lo (3-MFMA products, rel err ~2^-17).
// POST-MORTEMS baked in:
//  r4: LDS XOR-swizzle in main_gemm regressed -> keep linear stride-40 layout.
//  r5: cooperative grid.sync fusion = 983us barrier spin -> multi-launch only.
//  r6: 2-dt main_gemm spilled (2.1GB scratch traffic) -> single-dt kept.
//  r7: sq_mm folded as rider blocks into finals/ks launches (worked; kept).
//  r8: register prefetch in mm64_tile/ks_tile + K-doubling riders (worked; kept).
//  r9: carry-phase register prefetch one kt ahead (worked; 177->165us). BEST: 332us.
//  r10: stride 36: conflicts halved, dur flat -> conflicts not binding (reverted to 40).
//  r11: A-from-global regressed (latency-exposed dependent loads) -> reverted.
//  r12: single-barrier dbuf regressed (LDS 72KB -> 2 blocks/CU) -> reverted.
//  r13: XCD dt-swizzle regressed (FETCH 72->271MB, VGPR 120) -> reverted.
//  r14: = r9 file + T5 s_setprio(1) around main_gemm MFMA cluster (blocks are
//       mutually unsynchronized -> wave role diversity -> setprio regime).

#define N 256
#define LSEQ 4096
#define BATCH 64
#define TCH 64
#define NCH 64

using bf16x8 = __attribute__((ext_vector_type(8))) __bf16;
using f32x4  = __attribute__((ext_vector_type(4))) float;

__device__ __forceinline__ unsigned short f2bf(float f) {
  uint32_t x = __builtin_bit_cast(uint32_t, f);
  uint32_t r = x + 0x7fffu + ((x >> 16) & 1u);
  return (unsigned short)(r >> 16);
}
__device__ __forceinline__ float bf2f(unsigned short h) {
  uint32_t x = ((uint32_t)h) << 16;
  return __builtin_bit_cast(float, x);
}

__device__ __forceinline__ int swz(int r, int c) { return r * 32 + ((c ^ ((r >> 1) & 3)) << 3); }

// ws offsets (bytes)
#define OFF_Phi 16777216
#define OFF_Plo 25165824
#define OFF_Kf  33554432
#define OFF_Khi 33619968
#define OFF_Klo 33652736
#define OFF_shi 33685504
#define OFF_slo 35782656
#define OFF_G0  37879808
#define OFF_uT  42074112
#define OFF_Sqh 43122688
#define OFF_Sql 43778048

// ---------- device phase bodies ----------

// 64x64 fp32 GEMM tile with k0-prefetch: C = A @ B, fp32 C + bf16 hi/lo split.
__device__ __forceinline__ void mm64_tile(const float* __restrict__ A, const float* __restrict__ B,
                                          float* __restrict__ Cw, unsigned short* __restrict__ Chi,
                                          unsigned short* __restrict__ Clo, int bx, int tid,
                                          char* smem) {
  float (*At)[68] = (float(*)[68])smem;
  float (*Bs)[68] = (float(*)[68])(smem + 4352);
  int gr0 = (bx >> 2) * 64, gc0 = (bx & 3) * 64;
  int ty = tid >> 4, tx = tid & 15;
  float acc[4][4];
  #pragma unroll
  for (int r = 0; r < 4; ++r)
    #pragma unroll
    for (int c = 0; c < 4; ++c) acc[r][c] = 0.f;
  int ra = tid >> 2, ka4 = (tid & 3) << 2;
  int kb = tid >> 4, cb4 = (tid & 15) << 2;
  const float* pa = &A[(size_t)(gr0 + ra) * 256 + ka4];
  const float* pb = &B[(size_t)kb * 256 + gc0 + cb4];
  float4 va = *(const float4*)pa;
  float4 vb = *(const float4*)pb;
  for (int k0 = 0; k0 < 256; k0 += 16) {
    At[ka4 + 0][ra] = va.x; At[ka4 + 1][ra] = va.y;
    At[ka4 + 2][ra] = va.z; At[ka4 + 3][ra] = va.w;
    *(float4*)&Bs[kb][cb4] = vb;
    __syncthreads();
    if (k0 + 16 < 256) {
      va = *(const float4*)(pa + k0 + 16);
      vb = *(const float4*)(pb + (size_t)(k0 + 16) * 256);
    }
    #pragma unroll
    for (int kk = 0; kk < 16; ++kk) {
      float4 a4 = *(const float4*)&At[kk][ty << 2];
      float4 b4 = *(const float4*)&Bs[kk][tx << 2];
      acc[0][0] += a4.x * b4.x; acc[0][1] += a4.x * b4.y; acc[0][2] += a4.x * b4.z; acc[0][3] += a4.x * b4.w;
      acc[1][0] += a4.y * b4.x; acc[1][1] += a4.y * b4.y; acc[1][2] += a4.y * b4.z; acc[1][3] += a4.y * b4.w;
      acc[2][0] += a4.z * b4.x; acc[2][1] += a4.z * b4.y; acc[2][2] += a4.z * b4.z; acc[2][3] += a4.z * b4.w;
      acc[3][0] += a4.w * b4.x; acc[3][1] += a4.w * b4.y; acc[3][2] += a4.w * b4.z; acc[3][3] += a4.w * b4.w;
    }
    __syncthreads();
  }
  #pragma unroll
  for (int r = 0; r < 4; ++r)
    #pragma unroll
    for (int c = 0; c < 4; ++c) {
      size_t idx = (size_t)(gr0 + ty * 4 + r) * 256 + gc0 + tx * 4 + c;
      float v = acc[r][c];
      Cw[idx] = v;
      unsigned short h = f2bf(v);
      Chi[idx] = h;
      Clo[idx] = f2bf(v - bf2f(h));
    }
}

__device__ __forceinline__ void finals_one(const float* __restrict__ Kf, const float* __restrict__ u,
                                           float* __restrict__ G0, int k, int b, int i) {
  float acc = 0.f;
  int ubase = (k * TCH + 63) * BATCH + b;
  #pragma unroll 8
  for (int p = 0; p < TCH; ++p)
    acc += Kf[p * N + i] * u[ubase - p * BATCH];
  G0[(size_t)(k * BATCH + b) * N + i] = acc;
}

// one Kogge-Stone 64x64 tile with kt-prefetch: Gout[m] = Gin[m] + Gin[m-shift] @ M^T.
template <int FINAL>
__device__ __forceinline__ void ks_tile(int bx, int tid, const float* __restrict__ Gin,
                                        float* __restrict__ Gout,
                                        const unsigned short* __restrict__ Mh,
                                        const unsigned short* __restrict__ Ml, int shift,
                                        unsigned short* __restrict__ shi,
                                        unsigned short* __restrict__ slo, char* smem) {
  unsigned short* Ah = (unsigned short*)smem;
  unsigned short* Al = (unsigned short*)(smem + 4096);
  unsigned short* Bh = (unsigned short*)(smem + 8192);
  unsigned short* Bl = (unsigned short*)(smem + 12288);
  int kb0 = (bx >> 2) * 64, i0 = (bx & 3) * 64;
  int lane = tid & 63, wid = tid >> 6;
  int wr = wid >> 1, wc = wid & 1;
  int rg = lane >> 4, cl = lane & 15;

  f32x4 acc[2][2];
  #pragma unroll
  for (int mf = 0; mf < 2; ++mf) {
    int m0 = kb0 + wr * 32 + mf * 16 + rg * 4;
    #pragma unroll
    for (int nf = 0; nf < 2; ++nf) {
      int i = i0 + wc * 32 + nf * 16 + cl;
      #pragma unroll
      for (int r = 0; r < 4; ++r)
        acc[mf][nf][r] = Gin[(size_t)(m0 + r) * 256 + i];
    }
  }

  int sr = tid >> 2, kc = tid & 3;
  int sw = swz(sr, kc);
  int srow = kb0 + sr - shift;
  bool haveA = (srow >= 0);
  const float* srcA = &Gin[(size_t)(haveA ? srow : 0) * 256 + kc * 8];
  const unsigned short* srcBh = &Mh[(size_t)(i0 + sr) * 256 + kc * 8];
  const unsigned short* srcBl = &Ml[(size_t)(i0 + sr) * 256 + kc * 8];

  float4 rA0, rA1;
  uint4 rBh = *(const uint4*)srcBh, rBl = *(const uint4*)srcBl;
  if (haveA) { rA0 = *(const float4*)srcA; rA1 = *(const float4*)(srcA + 4); }

  for (int kt = 0; kt < 8; ++kt) {
    if (haveA) {
      float vv[8] = {rA0.x, rA0.y, rA0.z, rA0.w, rA1.x, rA1.y, rA1.z, rA1.w};
      unsigned short hv[8], lv[8];
      #pragma unroll
      for (int e = 0; e < 8; ++e) {
        hv[e] = f2bf(vv[e]);
        lv[e] = f2bf(vv[e] - bf2f(hv[e]));
      }
      *(uint4*)&Ah[sw] = *(const uint4*)hv;
      *(uint4*)&Al[sw] = *(const uint4*)lv;
    } else {
      uint4 z = {0, 0, 0, 0};
      *(uint4*)&Ah[sw] = z;
      *(uint4*)&Al[sw] = z;
    }
    *(uint4*)&Bh[sw] = rBh;
    *(uint4*)&Bl[sw] = rBl;
    __syncthreads();

    if (kt < 7) {
      int off = (kt + 1) * 32;
      if (haveA) { rA0 = *(const float4*)(srcA + off); rA1 = *(const float4*)(srcA + off + 4); }
      rBh = *(const uint4*)(srcBh + off);
      rBl = *(const uint4*)(srcBl + off);
    }

    int fr = lane & 15, kseg = lane >> 4;
    bf16x8 ah[2], al[2], bh[2], bl[2];
    #pragma unroll
    for (int mf = 0; mf < 2; ++mf) {
      int row = wr * 32 + mf * 16 + fr;
      ah[mf] = *(const bf16x8*)&Ah[swz(row, kseg)];
      al[mf] = *(const bf16x8*)&Al[swz(row, kseg)];
    }
    #pragma unroll
    for (int nf = 0; nf < 2; ++nf) {
      int row = wc * 32 + nf * 16 + fr;
      bh[nf] = *(const bf16x8*)&Bh[swz(row, kseg)];
      bl[nf] = *(const bf16x8*)&Bl[swz(row, kseg)];
    }
    #pragma unroll
    for (int mf = 0; mf < 2; ++mf)
      #pragma unroll
      for (int nf = 0; nf < 2; ++nf) {
        acc[mf][nf] = __builtin_amdgcn_mfma_f32_16x16x32_bf16(ah[mf], bh[nf], acc[mf][nf], 0, 0, 0);
        acc[mf][nf] = __builtin_amdgcn_mfma_f32_16x16x32_bf16(ah[mf], bl[nf], acc[mf][nf], 0, 0, 0);
        acc[mf][nf] = __builtin_amdgcn_mfma_f32_16x16x32_bf16(al[mf], bh[nf], acc[mf][nf], 0, 0, 0);
      }
    __syncthreads();
  }

  #pragma unroll
  for (int mf = 0; mf < 2; ++mf) {
    int m0 = kb0 + wr * 32 + mf * 16 + rg * 4;
    #pragma unroll
    for (int nf = 0; nf < 2; ++nf) {
      int i = i0 + wc * 32 + nf * 16 + cl;
      #pragma unroll
      for (int r = 0; r < 4; ++r) {
        if (FINAL) {
          int tm = m0 + r + 64;
          if (tm < 4096) {
            float v = acc[mf][nf][r];
            unsigned short h = f2bf(v);
            shi[(size_t)tm * 256 + i] = h;
            slo[(size_t)tm * 256 + i] = f2bf(v - bf2f(h));
          }
        } else {
          Gout[(size_t)(m0 + r) * 256 + i] = acc[mf][nf][r];
        }
      }
    }
  }
  if (FINAL && kb0 == 0) {
    for (int e = tid; e < 4096; e += 256) {
      size_t o = (size_t)(e >> 6) * 256 + i0 + (e & 63);
      shi[o] = 0;
      slo[o] = 0;
    }
  }
}

// ---------- standalone kernels ----------

// prep0: bid<64 transpose u; bid<128 dA copy/split; bid==128 K[0]=dB init.
__global__ __launch_bounds__(256) void prep0(const float* __restrict__ u, const float* __restrict__ dA,
                                             const float* __restrict__ dB,
                                             float* __restrict__ uT, float* __restrict__ Pw,
                                             unsigned short* __restrict__ Phi, unsigned short* __restrict__ Plo,
                                             float* __restrict__ Kf, unsigned short* __restrict__ Khi,
                                             unsigned short* __restrict__ Klo) {
  __shared__ float tile[64][65];
  int bid = blockIdx.x, tid = threadIdx.x;
  if (bid < 64) {
    int t0 = bid * 64;
    #pragma unroll
    for (int q = 0; q < 16; ++q) {
      int e = q * 256 + tid;
      int tt = e >> 6, b = e & 63;
      tile[b][tt] = u[(size_t)(t0 + tt) * 64 + b];
    }
    __syncthreads();
    #pragma unroll
    for (int q = 0; q < 16; ++q) {
      int e = q * 256 + tid;
      int b = e >> 6, tt = e & 63;
      uT[(size_t)b * 4096 + t0 + tt] = tile[b][tt];
    }
  } else if (bid < 128) {
    int base = (bid - 64) * 1024 + tid * 4;
    float4 v = *(const float4*)&dA[base];
    *(float4*)&Pw[base] = v;
    float vv[4] = {v.x, v.y, v.z, v.w};
    #pragma unroll
    for (int q = 0; q < 4; ++q) {
      unsigned short h = f2bf(vv[q]);
      Phi[base + q] = h;
      Plo[base + q] = f2bf(vv[q] - bf2f(h));
    }
  } else {
    float v = dB[tid];
    Kf[tid] = v;
    unsigned short h = f2bf(v);
    Khi[tid] = h;
    Klo[tid] = f2bf(v - bf2f(h));
  }
}

// pow_K: level half. Blocks [0,16*half): P[half+q] = P[q] @ P[half] (fp32 + split).
// Blocks [16*half, 20*half): K-riders, K[half+j] = P[half] . K[j] (wave row-dots).
__global__ __launch_bounds__(256) void pow_K(float* __restrict__ Pw,
                                             unsigned short* __restrict__ Phi,
                                             unsigned short* __restrict__ Plo,
                                             float* __restrict__ Kf,
                                             unsigned short* __restrict__ Khi,
                                             unsigned short* __restrict__ Klo,
                                             int half) {
  __shared__ __align__(16) char smem[16640];
  int bx = blockIdx.x, tid = threadIdx.x;
  if (bx < 16 * half) {
    int q = (bx >> 4) + 1, t = bx & 15;
    mm64_tile(Pw + (size_t)(q - 1) * 65536, Pw + (size_t)(half - 1) * 65536,
              Pw + (size_t)(half + q - 1) * 65536, Phi + (size_t)(half + q - 1) * 65536,
              Plo + (size_t)(half + q - 1) * 65536, t, tid, smem);
  } else {
    int r = bx - 16 * half;
    int jp = r >> 2, quarter = r & 3;
    int p = half + jp;
    const float* M = Pw + (size_t)(half - 1) * 65536;
    const float* v = Kf + (size_t)jp * 256;
    int lane = tid & 63, w = tid >> 6;
    float d0 = v[lane], d1 = v[lane + 64], d2 = v[lane + 128], d3 = v[lane + 192];
    for (int ii = 0; ii < 16; ++ii) {
      int i = quarter * 64 + w * 16 + ii;
      const float* row = M + (size_t)i * 256;
      float acc = row[lane] * d0 + row[lane + 64] * d1 + row[lane + 128] * d2 + row[lane + 192] * d3;
      #pragma unroll
      for (int off = 32; off; off >>= 1) acc += __shfl_xor(acc, off, 64);
      if (lane == 0) {
        Kf[p * 256 + i] = acc;
        unsigned short h = f2bf(acc);
        Khi[p * 256 + i] = h;
        Klo[p * 256 + i] = f2bf(acc - bf2f(h));
      }
    }
  }
}

// finals (grid 65 x 64) + folded sq0.
__global__ __launch_bounds__(256) void finals_sq(const float* __restrict__ Kf, const float* __restrict__ u,
                                                 float* __restrict__ G0,
                                                 const float* __restrict__ S0, float* __restrict__ S1,
                                                 unsigned short* __restrict__ Sqh0,
                                                 unsigned short* __restrict__ Sql0) {
  __shared__ __align__(16) char smem[16640];
  if (blockIdx.x < 64) {
    finals_one(Kf, u, G0, blockIdx.x, blockIdx.y, threadIdx.x);
  } else if (blockIdx.y < 16) {
    mm64_tile(S0, S0, S1, Sqh0, Sql0, blockIdx.y, threadIdx.x, smem);
  }
}

// ks_level + optional folded square: blocks >=256 compute SqC = SqA @ SqA (16 tiles).
template <int FINAL>
__global__ __launch_bounds__(256) void ks_level(const float* __restrict__ Gin, float* __restrict__ Gout,
                                                const unsigned short* __restrict__ Mh,
                                                const unsigned short* __restrict__ Ml, int shift,
                                                unsigned short* __restrict__ shi,
                                                unsigned short* __restrict__ slo,
                                                const float* __restrict__ SqA, float* __restrict__ SqC,
                                                unsigned short* __restrict__ SqChi,
                                                unsigned short* __restrict__ SqClo) {
  __shared__ __align__(16) char smem[16640];
  int bx = blockIdx.x;
  if (bx < 256) {
    ks_tile<FINAL>(bx, threadIdx.x, Gin, Gout, Mh, Ml, shift, shi, slo, smem);
  } else {
    mm64_tile(SqA, SqA, SqC, SqChi, SqClo, bx - 256, threadIdx.x, smem);
  }
}

// main_gemm: out[k*64+dt][b][i] = sum_j P[dt+1][i][j] s_k[b][j] + sum_{p<=dt} K[p][i] u[kT+dt-p][b]
// r9 proven version (stride-40 LDS, 2-barrier, carry-phase register prefetch one kt ahead)
// + r14 setprio around the MFMA cluster.
__global__ __launch_bounds__(256, 2) void main_gemm(const unsigned short* __restrict__ shi,
                                                    const unsigned short* __restrict__ slo,
                                                    const unsigned short* __restrict__ Phi,
                                                    const unsigned short* __restrict__ Plo,
                                                    const unsigned short* __restrict__ Khi,
                                                    const unsigned short* __restrict__ Klo,
                                                    const float* __restrict__ uT,
                                                    float* __restrict__ out) {
  __shared__ unsigned short Ah[128 * 40], Al[128 * 40], Bh[128 * 40], Bl[128 * 40];
  int dt = blockIdx.y;
  int x = blockIdx.x;
  int it = x >> 5, kbt = x & 31;
  int kb0 = kbt * 128, i0 = it * 128;
  int tid = threadIdx.x;
  int lane = tid & 63, wid = tid >> 6;
  int wr = wid >> 1, wc = wid & 1;

  f32x4 acc[4][4];
  #pragma unroll
  for (int mf = 0; mf < 4; ++mf)
    #pragma unroll
    for (int nf = 0; nf < 4; ++nf)
      #pragma unroll
      for (int r = 0; r < 4; ++r) acc[mf][nf][r] = 0.f;

  const unsigned short* PhiD = Phi + (size_t)dt * 65536;
  const unsigned short* PloD = Plo + (size_t)dt * 65536;
  int nkt = (dt >= 32) ? 10 : 9;

  // carry-phase staging bases (loop-invariant); prefetch regs hold kt's 8 uint4
  int r = tid >> 1, h = tid & 1;
  int lo_ = r * 40 + h * 16;
  const unsigned short* b1 = shi  + (size_t)(kb0 + r) * 256 + h * 16;
  const unsigned short* b2 = slo  + (size_t)(kb0 + r) * 256 + h * 16;
  const unsigned short* b3 = PhiD + (size_t)(i0 + r) * 256 + h * 16;
  const unsigned short* b4 = PloD + (size_t)(i0 + r) * 256 + h * 16;
  uint4 r1a = *(const uint4*)b1;
  uint4 r1b = *(const uint4*)(b1 + 8);
  uint4 r2a = *(const uint4*)b2;
  uint4 r2b = *(const uint4*)(b2 + 8);
  uint4 r3a = *(const uint4*)b3;
  uint4 r3b = *(const uint4*)(b3 + 8);
  uint4 r4a = *(const uint4*)b4;
  uint4 r4b = *(const uint4*)(b4 + 8);

  for (int kt = 0; kt < nkt; ++kt) {
    if (kt < 8) {
      *(uint4*)&Ah[lo_]     = r1a;
      *(uint4*)&Ah[lo_ + 8] = r1b;
      *(uint4*)&Al[lo_]     = r2a;
      *(uint4*)&Al[lo_ + 8] = r2b;
      *(uint4*)&Bh[lo_]     = r3a;
      *(uint4*)&Bh[lo_ + 8] = r3b;
      *(uint4*)&Bl[lo_]     = r4a;
      *(uint4*)&Bl[lo_ + 8] = r4b;
    } else {
      int p0 = (kt - 8) * 32;
      int kk = (kb0 + r) >> 6, b = (kb0 + r) & 63;
      const float* ub2 = uT + (size_t)b * 4096 + kk * 64 + dt;
      #pragma unroll
      for (int qq = 0; qq < 16; ++qq) {
        int pp = h * 16 + qq;
        int sh = p0 + pp;
        float v = (sh <= dt) ? ub2[-sh] : 0.f;
        unsigned short hv = f2bf(v);
        Ah[r * 40 + pp] = hv;
        Al[r * 40 + pp] = f2bf(v - bf2f(hv));
      }
      int n = tid & 127, ph = tid >> 7;
      #pragma unroll
      for (int qq = 0; qq < 16; ++qq) {
        int pp = ph * 16 + qq;
        Bh[n * 40 + pp] = Khi[(p0 + pp) * 256 + i0 + n];
        Bl[n * 40 + pp] = Klo[(p0 + pp) * 256 + i0 + n];
      }
    }
    __syncthreads();

    // issue next carry-phase loads early: latency hides under this kt's MFMAs
    if (kt + 1 < 8) {
      int co = (kt + 1) * 32;
      r1a = *(const uint4*)(b1 + co);
      r1b = *(const uint4*)(b1 + co + 8);
      r2a = *(const uint4*)(b2 + co);
      r2b = *(const uint4*)(b2 + co + 8);
      r3a = *(const uint4*)(b3 + co);
      r3b = *(const uint4*)(b3 + co + 8);
      r4a = *(const uint4*)(b4 + co);
      r4b = *(const uint4*)(b4 + co + 8);
    }

    int kseg = lane >> 4, fr = lane & 15;
    bf16x8 ah[4], al[4], bh[4], bl[4];
    #pragma unroll
    for (int mf = 0; mf < 4; ++mf) {
      int row = (wr * 64 + mf * 16 + fr) * 40 + kseg * 8;
      ah[mf] = *(const bf16x8*)&Ah[row];
      al[mf] = *(const bf16x8*)&Al[row];
    }
    #pragma unroll
    for (int nf = 0; nf < 4; ++nf) {
      int row = (wc * 64 + nf * 16 + fr) * 40 + kseg * 8;
      bh[nf] = *(const bf16x8*)&Bh[row];
      bl[nf] = *(const bf16x8*)&Bl[row];
    }
    __builtin_amdgcn_s_setprio(1);
    #pragma unroll
    for (int mf = 0; mf < 4; ++mf)
      #pragma unroll
      for (int nf = 0; nf < 4; ++nf) {
        acc[mf][nf] = __builtin_amdgcn_mfma_f32_16x16x32_bf16(ah[mf], bh[nf], acc[mf][nf], 0, 0, 0);
        acc[mf][nf] = __builtin_amdgcn_mfma_f32_16x16x32_bf16(ah[mf], bl[nf], acc[mf][nf], 0, 0, 0);
        acc[mf][nf] = __builtin_amdgcn_mfma_f32_16x16x32_bf16(al[mf], bh[nf], acc[mf][nf], 0, 0, 0);
      }
    __builtin_amdgcn_s_setprio(0);
    __syncthreads();
  }

  int rg = lane >> 4, cl = lane & 15;
  #pragma unroll
  for (int mf = 0; mf < 4; ++mf) {
    int kbrow_base = kb0 + wr * 64 + mf * 16 + rg * 4;
    #pragma unroll
    for (int nf = 0; nf < 4; ++nf) {
      int i = i0 + wc * 64 + nf * 16 + cl;
      #pragma unroll
      for (int rr = 0; rr < 4; ++rr) {
        int kbrow = kbrow_base + rr;
        int k = kbrow >> 6, b = kbrow & 63;
        size_t t = (size_t)(k * 64 + dt);
        out[(t * 64 + b) * 256 + i] = acc[mf][nf][rr];
      }
    }
  }
}

// ======================= HOST =======================

extern "C" void kernel_launch(void* const* d_in, const int* in_sizes, int n_in,
                              void* d_out, int out_size, void* d_ws, size_t ws_size,
                              hipStream_t stream) {
  (void)in_sizes; (void)n_in; (void)out_size;
  const float* u  = (const float*)d_in[0];
  const float* dA = (const float*)d_in[1];
  const float* dB = (const float*)d_in[2];
  float* out = (float*)d_out;
  char* ws = (char*)d_ws;

  float*          Pw  = (float*)(ws);
  unsigned short* Phi = (unsigned short*)(ws + OFF_Phi);
  unsigned short* Plo = (unsigned short*)(ws + OFF_Plo);
  float*          Kf  = (float*)(ws + OFF_Kf);
  unsigned short* Khi = (unsigned short*)(ws + OFF_Khi);
  unsigned short* Klo = (unsigned short*)(ws + OFF_Klo);
  unsigned short* shi = (unsigned short*)(ws + OFF_shi);
  unsigned short* slo = (unsigned short*)(ws + OFF_slo);
  float*          G0  = (float*)(ws + OFF_G0);
  unsigned short* Sqh = (unsigned short*)(ws + OFF_Sqh);
  unsigned short* Sql = (unsigned short*)(ws + OFF_Sql);

  const size_t NEED_KS = 44433408;
  if (ws_size < NEED_KS) return;  // proven available in prior rounds

  float* G1 = (float*)ws;  // aliases Pw slots 0..15 (dead once K built)

  // fp32 squares: S[0]=dA^64 (Pw slot 63); S[1..5] in Pw slots 56..60
  float* S[6];
  S[0] = Pw + (size_t)63 * 65536;
  for (int d = 1; d <= 5; ++d) S[d] = Pw + (size_t)(55 + d) * 65536;

  prep0<<<129, 256, 0, stream>>>(u, dA, dB, (float*)(ws + OFF_uT), Pw, Phi, Plo, Kf, Khi, Klo);
  for (int half = 1; half <= 32; half <<= 1)
    pow_K<<<20 * half, 256, 0, stream>>>(Pw, Phi, Plo, Kf, Khi, Klo, half);

  // finals + sq0 (M^2) folded
  finals_sq<<<dim3(65, 64), 256, 0, stream>>>(Kf, u, G0, S[0], S[1], Sqh, Sql);

  const unsigned short* Mh0 = Phi + (size_t)63 * 65536;
  const unsigned short* Ml0 = Plo + (size_t)63 * 65536;
  // ks L0 (+sq1: M^4), L1 (+sq2: M^8), L2 (+sq3: M^16), L3 (+sq4: M^32), L4, L5(final)
  ks_level<0><<<272, 256, 0, stream>>>(G0, G1, Mh0, Ml0, 64, nullptr, nullptr,
                                       S[1], S[2], Sqh + 1 * 65536, Sql + 1 * 65536);
  ks_level<0><<<272, 256, 0, stream>>>(G1, G0, Sqh + 0 * 65536, Sql + 0 * 65536, 128, nullptr, nullptr,
                                       S[2], S[3], Sqh + 2 * 65536, Sql + 2 * 65536);
  ks_level<0><<<272, 256, 0, stream>>>(G0, G1, Sqh + 1 * 65536, Sql + 1 * 65536, 256, nullptr, nullptr,
                                       S[3], S[4], Sqh + 3 * 65536, Sql + 3 * 65536);
  ks_level<0><<<272, 256, 0, stream>>>(G1, G0, Sqh + 2 * 65536, Sql + 2 * 65536, 512, nullptr, nullptr,
                                       S[4], S[5], Sqh + 4 * 65536, Sql + 4 * 65536);
  ks_level<0><<<256, 256, 0, stream>>>(G0, G1, Sqh + 3 * 65536, Sql + 3 * 65536, 1024, nullptr, nullptr,
                                       nullptr, nullptr, nullptr, nullptr);
  ks_level<1><<<256, 256, 0, stream>>>(G1, nullptr, Sqh + 4 * 65536, Sql + 4 * 65536, 2048, shi, slo,
                                       nullptr, nullptr, nullptr, nullptr);

  main_gemm<<<dim3(64, 64), 256, 0, stream>>>(shi, slo, Phi, Plo, Khi, Klo,
                                              (const float*)(ws + OFF_uT), out);
}

// Round 15
// 331.924 us; speedup vs baseline: 1.1344x; 1.0486x over previous
//
#include <hip/hip_runtime.h>
#include <hip/hip_bf16.h>
#include <stdint.h>

// HiPPO-LegT LTI scan: c_t = dA c_{t-1} + dB u_t, out = all c_t. N=256, L=4096, B=64.
//   c[k*64+dt] = dA^{dt+1} . s_k  +  sum_{p<=dt} (dA^p dB) . u[k*64+dt-p]   (main_gemm, MFMA)
//   s_k via Kogge-Stone over chunk finals (6 MFMA GEMM levels, 64x64 tiles, full chip).
// All fp32 data; MFMA operands split bf16 hi/lo (3-MFMA products, rel err ~2^-17).
// POST-MORTEMS baked in (FINAL = round-9 best configuration, 332us measured):
//  r4: LDS XOR-swizzle in main_gemm regressed -> keep linear stride-40 layout.
//  r5: cooperative grid.sync fusion = 983us barrier spin -> multi-launch only.
//  r6: 2-dt main_gemm spilled (2.1GB scratch traffic) -> single-dt kept.
//  r7: sq_mm folded as rider blocks into finals/ks launches (worked; kept).
//  r8: register prefetch in mm64_tile/ks_tile + K-doubling riders (worked; kept).
//  r9: carry-phase register prefetch one kt ahead (worked; 177->165us). BEST.
//  r10: stride 36: conflicts halved, dur flat -> conflicts not binding (kept 40).
//  r11: A-from-global regressed (latency-exposed dependent loads) -> reverted.
//  r12: single-barrier dbuf regressed (LDS 72KB -> 2 blocks/CU) -> reverted.
//  r13: XCD dt-swizzle regressed (FETCH 72->271MB, VGPR 120) -> reverted.
//  r14: setprio regressed (VGPR 96, occ 21%) -> reverted.

#define N 256
#define LSEQ 4096
#define BATCH 64
#define TCH 64
#define NCH 64

using bf16x8 = __attribute__((ext_vector_type(8))) __bf16;
using f32x4  = __attribute__((ext_vector_type(4))) float;

__device__ __forceinline__ unsigned short f2bf(float f) {
  uint32_t x = __builtin_bit_cast(uint32_t, f);
  uint32_t r = x + 0x7fffu + ((x >> 16) & 1u);
  return (unsigned short)(r >> 16);
}
__device__ __forceinline__ float bf2f(unsigned short h) {
  uint32_t x = ((uint32_t)h) << 16;
  return __builtin_bit_cast(float, x);
}

__device__ __forceinline__ int swz(int r, int c) { return r * 32 + ((c ^ ((r >> 1) & 3)) << 3); }

// ws offsets (bytes)
#define OFF_Phi 16777216
#define OFF_Plo 25165824
#define OFF_Kf  33554432
#define OFF_Khi 33619968
#define OFF_Klo 33652736
#define OFF_shi 33685504
#define OFF_slo 35782656
#define OFF_G0  37879808
#define OFF_uT  42074112
#define OFF_Sqh 43122688
#define OFF_Sql 43778048

// ---------- device phase bodies ----------

// 64x64 fp32 GEMM tile with k0-prefetch: C = A @ B, fp32 C + bf16 hi/lo split.
__device__ __forceinline__ void mm64_tile(const float* __restrict__ A, const float* __restrict__ B,
                                          float* __restrict__ Cw, unsigned short* __restrict__ Chi,
                                          unsigned short* __restrict__ Clo, int bx, int tid,
                                          char* smem) {
  float (*At)[68] = (float(*)[68])smem;
  float (*Bs)[68] = (float(*)[68])(smem + 4352);
  int gr0 = (bx >> 2) * 64, gc0 = (bx & 3) * 64;
  int ty = tid >> 4, tx = tid & 15;
  float acc[4][4];
  #pragma unroll
  for (int r = 0; r < 4; ++r)
    #pragma unroll
    for (int c = 0; c < 4; ++c) acc[r][c] = 0.f;
  int ra = tid >> 2, ka4 = (tid & 3) << 2;
  int kb = tid >> 4, cb4 = (tid & 15) << 2;
  const float* pa = &A[(size_t)(gr0 + ra) * 256 + ka4];
  const float* pb = &B[(size_t)kb * 256 + gc0 + cb4];
  float4 va = *(const float4*)pa;
  float4 vb = *(const float4*)pb;
  for (int k0 = 0; k0 < 256; k0 += 16) {
    At[ka4 + 0][ra] = va.x; At[ka4 + 1][ra] = va.y;
    At[ka4 + 2][ra] = va.z; At[ka4 + 3][ra] = va.w;
    *(float4*)&Bs[kb][cb4] = vb;
    __syncthreads();
    if (k0 + 16 < 256) {
      va = *(const float4*)(pa + k0 + 16);
      vb = *(const float4*)(pb + (size_t)(k0 + 16) * 256);
    }
    #pragma unroll
    for (int kk = 0; kk < 16; ++kk) {
      float4 a4 = *(const float4*)&At[kk][ty << 2];
      float4 b4 = *(const float4*)&Bs[kk][tx << 2];
      acc[0][0] += a4.x * b4.x; acc[0][1] += a4.x * b4.y; acc[0][2] += a4.x * b4.z; acc[0][3] += a4.x * b4.w;
      acc[1][0] += a4.y * b4.x; acc[1][1] += a4.y * b4.y; acc[1][2] += a4.y * b4.z; acc[1][3] += a4.y * b4.w;
      acc[2][0] += a4.z * b4.x; acc[2][1] += a4.z * b4.y; acc[2][2] += a4.z * b4.z; acc[2][3] += a4.z * b4.w;
      acc[3][0] += a4.w * b4.x; acc[3][1] += a4.w * b4.y; acc[3][2] += a4.w * b4.z; acc[3][3] += a4.w * b4.w;
    }
    __syncthreads();
  }
  #pragma unroll
  for (int r = 0; r < 4; ++r)
    #pragma unroll
    for (int c = 0; c < 4; ++c) {
      size_t idx = (size_t)(gr0 + ty * 4 + r) * 256 + gc0 + tx * 4 + c;
      float v = acc[r][c];
      Cw[idx] = v;
      unsigned short h = f2bf(v);
      Chi[idx] = h;
      Clo[idx] = f2bf(v - bf2f(h));
    }
}

__device__ __forceinline__ void finals_one(const float* __restrict__ Kf, const float* __restrict__ u,
                                           float* __restrict__ G0, int k, int b, int i) {
  float acc = 0.f;
  int ubase = (k * TCH + 63) * BATCH + b;
  #pragma unroll 8
  for (int p = 0; p < TCH; ++p)
    acc += Kf[p * N + i] * u[ubase - p * BATCH];
  G0[(size_t)(k * BATCH + b) * N + i] = acc;
}

// one Kogge-Stone 64x64 tile with kt-prefetch: Gout[m] = Gin[m] + Gin[m-shift] @ M^T.
template <int FINAL>
__device__ __forceinline__ void ks_tile(int bx, int tid, const float* __restrict__ Gin,
                                        float* __restrict__ Gout,
                                        const unsigned short* __restrict__ Mh,
                                        const unsigned short* __restrict__ Ml, int shift,
                                        unsigned short* __restrict__ shi,
                                        unsigned short* __restrict__ slo, char* smem) {
  unsigned short* Ah = (unsigned short*)smem;
  unsigned short* Al = (unsigned short*)(smem + 4096);
  unsigned short* Bh = (unsigned short*)(smem + 8192);
  unsigned short* Bl = (unsigned short*)(smem + 12288);
  int kb0 = (bx >> 2) * 64, i0 = (bx & 3) * 64;
  int lane = tid & 63, wid = tid >> 6;
  int wr = wid >> 1, wc = wid & 1;
  int rg = lane >> 4, cl = lane & 15;

  f32x4 acc[2][2];
  #pragma unroll
  for (int mf = 0; mf < 2; ++mf) {
    int m0 = kb0 + wr * 32 + mf * 16 + rg * 4;
    #pragma unroll
    for (int nf = 0; nf < 2; ++nf) {
      int i = i0 + wc * 32 + nf * 16 + cl;
      #pragma unroll
      for (int r = 0; r < 4; ++r)
        acc[mf][nf][r] = Gin[(size_t)(m0 + r) * 256 + i];
    }
  }

  int sr = tid >> 2, kc = tid & 3;
  int sw = swz(sr, kc);
  int srow = kb0 + sr - shift;
  bool haveA = (srow >= 0);
  const float* srcA = &Gin[(size_t)(haveA ? srow : 0) * 256 + kc * 8];
  const unsigned short* srcBh = &Mh[(size_t)(i0 + sr) * 256 + kc * 8];
  const unsigned short* srcBl = &Ml[(size_t)(i0 + sr) * 256 + kc * 8];

  float4 rA0, rA1;
  uint4 rBh = *(const uint4*)srcBh, rBl = *(const uint4*)srcBl;
  if (haveA) { rA0 = *(const float4*)srcA; rA1 = *(const float4*)(srcA + 4); }

  for (int kt = 0; kt < 8; ++kt) {
    if (haveA) {
      float vv[8] = {rA0.x, rA0.y, rA0.z, rA0.w, rA1.x, rA1.y, rA1.z, rA1.w};
      unsigned short hv[8], lv[8];
      #pragma unroll
      for (int e = 0; e < 8; ++e) {
        hv[e] = f2bf(vv[e]);
        lv[e] = f2bf(vv[e] - bf2f(hv[e]));
      }
      *(uint4*)&Ah[sw] = *(const uint4*)hv;
      *(uint4*)&Al[sw] = *(const uint4*)lv;
    } else {
      uint4 z = {0, 0, 0, 0};
      *(uint4*)&Ah[sw] = z;
      *(uint4*)&Al[sw] = z;
    }
    *(uint4*)&Bh[sw] = rBh;
    *(uint4*)&Bl[sw] = rBl;
    __syncthreads();

    if (kt < 7) {
      int off = (kt + 1) * 32;
      if (haveA) { rA0 = *(const float4*)(srcA + off); rA1 = *(const float4*)(srcA + off + 4); }
      rBh = *(const uint4*)(srcBh + off);
      rBl = *(const uint4*)(srcBl + off);
    }

    int fr = lane & 15, kseg = lane >> 4;
    bf16x8 ah[2], al[2], bh[2], bl[2];
    #pragma unroll
    for (int mf = 0; mf < 2; ++mf) {
      int row = wr * 32 + mf * 16 + fr;
      ah[mf] = *(const bf16x8*)&Ah[swz(row, kseg)];
      al[mf] = *(const bf16x8*)&Al[swz(row, kseg)];
    }
    #pragma unroll
    for (int nf = 0; nf < 2; ++nf) {
      int row = wc * 32 + nf * 16 + fr;
      bh[nf] = *(const bf16x8*)&Bh[swz(row, kseg)];
      bl[nf] = *(const bf16x8*)&Bl[swz(row, kseg)];
    }
    #pragma unroll
    for (int mf = 0; mf < 2; ++mf)
      #pragma unroll
      for (int nf = 0; nf < 2; ++nf) {
        acc[mf][nf] = __builtin_amdgcn_mfma_f32_16x16x32_bf16(ah[mf], bh[nf], acc[mf][nf], 0, 0, 0);
        acc[mf][nf] = __builtin_amdgcn_mfma_f32_16x16x32_bf16(ah[mf], bl[nf], acc[mf][nf], 0, 0, 0);
        acc[mf][nf] = __builtin_amdgcn_mfma_f32_16x16x32_bf16(al[mf], bh[nf], acc[mf][nf], 0, 0, 0);
      }
    __syncthreads();
  }

  #pragma unroll
  for (int mf = 0; mf < 2; ++mf) {
    int m0 = kb0 + wr * 32 + mf * 16 + rg * 4;
    #pragma unroll
    for (int nf = 0; nf < 2; ++nf) {
      int i = i0 + wc * 32 + nf * 16 + cl;
      #pragma unroll
      for (int r = 0; r < 4; ++r) {
        if (FINAL) {
          int tm = m0 + r + 64;
          if (tm < 4096) {
            float v = acc[mf][nf][r];
            unsigned short h = f2bf(v);
            shi[(size_t)tm * 256 + i] = h;
            slo[(size_t)tm * 256 + i] = f2bf(v - bf2f(h));
          }
        } else {
          Gout[(size_t)(m0 + r) * 256 + i] = acc[mf][nf][r];
        }
      }
    }
  }
  if (FINAL && kb0 == 0) {
    for (int e = tid; e < 4096; e += 256) {
      size_t o = (size_t)(e >> 6) * 256 + i0 + (e & 63);
      shi[o] = 0;
      slo[o] = 0;
    }
  }
}

// ---------- standalone kernels ----------

// prep0: bid<64 transpose u; bid<128 dA copy/split; bid==128 K[0]=dB init.
__global__ __launch_bounds__(256) void prep0(const float* __restrict__ u, const float* __restrict__ dA,
                                             const float* __restrict__ dB,
                                             float* __restrict__ uT, float* __restrict__ Pw,
                                             unsigned short* __restrict__ Phi, unsigned short* __restrict__ Plo,
                                             float* __restrict__ Kf, unsigned short* __restrict__ Khi,
                                             unsigned short* __restrict__ Klo) {
  __shared__ float tile[64][65];
  int bid = blockIdx.x, tid = threadIdx.x;
  if (bid < 64) {
    int t0 = bid * 64;
    #pragma unroll
    for (int q = 0; q < 16; ++q) {
      int e = q * 256 + tid;
      int tt = e >> 6, b = e & 63;
      tile[b][tt] = u[(size_t)(t0 + tt) * 64 + b];
    }
    __syncthreads();
    #pragma unroll
    for (int q = 0; q < 16; ++q) {
      int e = q * 256 + tid;
      int b = e >> 6, tt = e & 63;
      uT[(size_t)b * 4096 + t0 + tt] = tile[b][tt];
    }
  } else if (bid < 128) {
    int base = (bid - 64) * 1024 + tid * 4;
    float4 v = *(const float4*)&dA[base];
    *(float4*)&Pw[base] = v;
    float vv[4] = {v.x, v.y, v.z, v.w};
    #pragma unroll
    for (int q = 0; q < 4; ++q) {
      unsigned short h = f2bf(vv[q]);
      Phi[base + q] = h;
      Plo[base + q] = f2bf(vv[q] - bf2f(h));
    }
  } else {
    float v = dB[tid];
    Kf[tid] = v;
    unsigned short h = f2bf(v);
    Khi[tid] = h;
    Klo[tid] = f2bf(v - bf2f(h));
  }
}

// pow_K: level half. Blocks [0,16*half): P[half+q] = P[q] @ P[half] (fp32 + split).
// Blocks [16*half, 20*half): K-riders, K[half+j] = P[half] . K[j] (wave row-dots).
__global__ __launch_bounds__(256) void pow_K(float* __restrict__ Pw,
                                             unsigned short* __restrict__ Phi,
                                             unsigned short* __restrict__ Plo,
                                             float* __restrict__ Kf,
                                             unsigned short* __restrict__ Khi,
                                             unsigned short* __restrict__ Klo,
                                             int half) {
  __shared__ __align__(16) char smem[16640];
  int bx = blockIdx.x, tid = threadIdx.x;
  if (bx < 16 * half) {
    int q = (bx >> 4) + 1, t = bx & 15;
    mm64_tile(Pw + (size_t)(q - 1) * 65536, Pw + (size_t)(half - 1) * 65536,
              Pw + (size_t)(half + q - 1) * 65536, Phi + (size_t)(half + q - 1) * 65536,
              Plo + (size_t)(half + q - 1) * 65536, t, tid, smem);
  } else {
    int r = bx - 16 * half;
    int jp = r >> 2, quarter = r & 3;
    int p = half + jp;
    const float* M = Pw + (size_t)(half - 1) * 65536;
    const float* v = Kf + (size_t)jp * 256;
    int lane = tid & 63, w = tid >> 6;
    float d0 = v[lane], d1 = v[lane + 64], d2 = v[lane + 128], d3 = v[lane + 192];
    for (int ii = 0; ii < 16; ++ii) {
      int i = quarter * 64 + w * 16 + ii;
      const float* row = M + (size_t)i * 256;
      float acc = row[lane] * d0 + row[lane + 64] * d1 + row[lane + 128] * d2 + row[lane + 192] * d3;
      #pragma unroll
      for (int off = 32; off; off >>= 1) acc += __shfl_xor(acc, off, 64);
      if (lane == 0) {
        Kf[p * 256 + i] = acc;
        unsigned short h = f2bf(acc);
        Khi[p * 256 + i] = h;
        Klo[p * 256 + i] = f2bf(acc - bf2f(h));
      }
    }
  }
}

// finals (grid 65 x 64) + folded sq0.
__global__ __launch_bounds__(256) void finals_sq(const float* __restrict__ Kf, const float* __restrict__ u,
                                                 float* __restrict__ G0,
                                                 const float* __restrict__ S0, float* __restrict__ S1,
                                                 unsigned short* __restrict__ Sqh0,
                                                 unsigned short* __restrict__ Sql0) {
  __shared__ __align__(16) char smem[16640];
  if (blockIdx.x < 64) {
    finals_one(Kf, u, G0, blockIdx.x, blockIdx.y, threadIdx.x);
  } else if (blockIdx.y < 16) {
    mm64_tile(S0, S0, S1, Sqh0, Sql0, blockIdx.y, threadIdx.x, smem);
  }
}

// ks_level + optional folded square: blocks >=256 compute SqC = SqA @ SqA (16 tiles).
template <int FINAL>
__global__ __launch_bounds__(256) void ks_level(const float* __restrict__ Gin, float* __restrict__ Gout,
                                                const unsigned short* __restrict__ Mh,
                                                const unsigned short* __restrict__ Ml, int shift,
                                                unsigned short* __restrict__ shi,
                                                unsigned short* __restrict__ slo,
                                                const float* __restrict__ SqA, float* __restrict__ SqC,
                                                unsigned short* __restrict__ SqChi,
                                                unsigned short* __restrict__ SqClo) {
  __shared__ __align__(16) char smem[16640];
  int bx = blockIdx.x;
  if (bx < 256) {
    ks_tile<FINAL>(bx, threadIdx.x, Gin, Gout, Mh, Ml, shift, shi, slo, smem);
  } else {
    mm64_tile(SqA, SqA, SqC, SqChi, SqClo, bx - 256, threadIdx.x, smem);
  }
}

// main_gemm: out[k*64+dt][b][i] = sum_j P[dt+1][i][j] s_k[b][j] + sum_{p<=dt} K[p][i] u[kT+dt-p][b]
// r9 proven version: stride-40 LDS, 2-barrier, carry-phase register prefetch one kt ahead.
__global__ __launch_bounds__(256, 2) void main_gemm(const unsigned short* __restrict__ shi,
                                                    const unsigned short* __restrict__ slo,
                                                    const unsigned short* __restrict__ Phi,
                                                    const unsigned short* __restrict__ Plo,
                                                    const unsigned short* __restrict__ Khi,
                                                    const unsigned short* __restrict__ Klo,
                                                    const float* __restrict__ uT,
                                                    float* __restrict__ out) {
  __shared__ unsigned short Ah[128 * 40], Al[128 * 40], Bh[128 * 40], Bl[128 * 40];
  int dt = blockIdx.y;
  int x = blockIdx.x;
  int it = x >> 5, kbt = x & 31;
  int kb0 = kbt * 128, i0 = it * 128;
  int tid = threadIdx.x;
  int lane = tid & 63, wid = tid >> 6;
  int wr = wid >> 1, wc = wid & 1;

  f32x4 acc[4][4];
  #pragma unroll
  for (int mf = 0; mf < 4; ++mf)
    #pragma unroll
    for (int nf = 0; nf < 4; ++nf)
      #pragma unroll
      for (int r = 0; r < 4; ++r) acc[mf][nf][r] = 0.f;

  const unsigned short* PhiD = Phi + (size_t)dt * 65536;
  const unsigned short* PloD = Plo + (size_t)dt * 65536;
  int nkt = (dt >= 32) ? 10 : 9;

  // carry-phase staging bases (loop-invariant); prefetch regs hold kt's 8 uint4
  int r = tid >> 1, h = tid & 1;
  int lo_ = r * 40 + h * 16;
  const unsigned short* b1 = shi  + (size_t)(kb0 + r) * 256 + h * 16;
  const unsigned short* b2 = slo  + (size_t)(kb0 + r) * 256 + h * 16;
  const unsigned short* b3 = PhiD + (size_t)(i0 + r) * 256 + h * 16;
  const unsigned short* b4 = PloD + (size_t)(i0 + r) * 256 + h * 16;
  uint4 r1a = *(const uint4*)b1;
  uint4 r1b = *(const uint4*)(b1 + 8);
  uint4 r2a = *(const uint4*)b2;
  uint4 r2b = *(const uint4*)(b2 + 8);
  uint4 r3a = *(const uint4*)b3;
  uint4 r3b = *(const uint4*)(b3 + 8);
  uint4 r4a = *(const uint4*)b4;
  uint4 r4b = *(const uint4*)(b4 + 8);

  for (int kt = 0; kt < nkt; ++kt) {
    if (kt < 8) {
      *(uint4*)&Ah[lo_]     = r1a;
      *(uint4*)&Ah[lo_ + 8] = r1b;
      *(uint4*)&Al[lo_]     = r2a;
      *(uint4*)&Al[lo_ + 8] = r2b;
      *(uint4*)&Bh[lo_]     = r3a;
      *(uint4*)&Bh[lo_ + 8] = r3b;
      *(uint4*)&Bl[lo_]     = r4a;
      *(uint4*)&Bl[lo_ + 8] = r4b;
    } else {
      int p0 = (kt - 8) * 32;
      int kk = (kb0 + r) >> 6, b = (kb0 + r) & 63;
      const float* ub2 = uT + (size_t)b * 4096 + kk * 64 + dt;
      #pragma unroll
      for (int qq = 0; qq < 16; ++qq) {
        int pp = h * 16 + qq;
        int sh = p0 + pp;
        float v = (sh <= dt) ? ub2[-sh] : 0.f;
        unsigned short hv = f2bf(v);
        Ah[r * 40 + pp] = hv;
        Al[r * 40 + pp] = f2bf(v - bf2f(hv));
      }
      int n = tid & 127, ph = tid >> 7;
      #pragma unroll
      for (int qq = 0; qq < 16; ++qq) {
        int pp = ph * 16 + qq;
        Bh[n * 40 + pp] = Khi[(p0 + pp) * 256 + i0 + n];
        Bl[n * 40 + pp] = Klo[(p0 + pp) * 256 + i0 + n];
      }
    }
    __syncthreads();

    // issue next carry-phase loads early: latency hides under this kt's MFMAs
    if (kt + 1 < 8) {
      int co = (kt + 1) * 32;
      r1a = *(const uint4*)(b1 + co);
      r1b = *(const uint4*)(b1 + co + 8);
      r2a = *(const uint4*)(b2 + co);
      r2b = *(const uint4*)(b2 + co + 8);
      r3a = *(const uint4*)(b3 + co);
      r3b = *(const uint4*)(b3 + co + 8);
      r4a = *(const uint4*)(b4 + co);
      r4b = *(const uint4*)(b4 + co + 8);
    }

    int kseg = lane >> 4, fr = lane & 15;
    bf16x8 ah[4], al[4], bh[4], bl[4];
    #pragma unroll
    for (int mf = 0; mf < 4; ++mf) {
      int row = (wr * 64 + mf * 16 + fr) * 40 + kseg * 8;
      ah[mf] = *(const bf16x8*)&Ah[row];
      al[mf] = *(const bf16x8*)&Al[row];
    }
    #pragma unroll
    for (int nf = 0; nf < 4; ++nf) {
      int row = (wc * 64 + nf * 16 + fr) * 40 + kseg * 8;
      bh[nf] = *(const bf16x8*)&Bh[row];
      bl[nf] = *(const bf16x8*)&Bl[row];
    }
    #pragma unroll
    for (int mf = 0; mf < 4; ++mf)
      #pragma unroll
      for (int nf = 0; nf < 4; ++nf) {
        acc[mf][nf] = __builtin_amdgcn_mfma_f32_16x16x32_bf16(ah[mf], bh[nf], acc[mf][nf], 0, 0, 0);
        acc[mf][nf] = __builtin_amdgcn_mfma_f32_16x16x32_bf16(ah[mf], bl[nf], acc[mf][nf], 0, 0, 0);
        acc[mf][nf] = __builtin_amdgcn_mfma_f32_16x16x32_bf16(al[mf], bh[nf], acc[mf][nf], 0, 0, 0);
      }
    __syncthreads();
  }

  int rg = lane >> 4, cl = lane & 15;
  #pragma unroll
  for (int mf = 0; mf < 4; ++mf) {
    int kbrow_base = kb0 + wr * 64 + mf * 16 + rg * 4;
    #pragma unroll
    for (int nf = 0; nf < 4; ++nf) {
      int i = i0 + wc * 64 + nf * 16 + cl;
      #pragma unroll
      for (int rr = 0; rr < 4; ++rr) {
        int kbrow = kbrow_base + rr;
        int k = kbrow >> 6, b = kbrow & 63;
        size_t t = (size_t)(k * 64 + dt);
        out[(t * 64 + b) * 256 + i] = acc[mf][nf][rr];
      }
    }
  }
}

// ======================= HOST =======================

extern "C" void kernel_launch(void* const* d_in, const int* in_sizes, int n_in,
                              void* d_out, int out_size, void* d_ws, size_t ws_size,
                              hipStream_t stream) {
  (void)in_sizes; (void)n_in; (void)out_size;
  const float* u  = (const float*)d_in[0];
  const float* dA = (const float*)d_in[1];
  const float* dB = (const float*)d_in[2];
  float* out = (float*)d_out;
  char* ws = (char*)d_ws;

  float*          Pw  = (float*)(ws);
  unsigned short* Phi = (unsigned short*)(ws + OFF_Phi);
  unsigned short* Plo = (unsigned short*)(ws + OFF_Plo);
  float*          Kf  = (float*)(ws + OFF_Kf);
  unsigned short* Khi = (unsigned short*)(ws + OFF_Khi);
  unsigned short* Klo = (unsigned short*)(ws + OFF_Klo);
  unsigned short* shi = (unsigned short*)(ws + OFF_shi);
  unsigned short* slo = (unsigned short*)(ws + OFF_slo);
  float*          G0  = (float*)(ws + OFF_G0);
  unsigned short* Sqh = (unsigned short*)(ws + OFF_Sqh);
  unsigned short* Sql = (unsigned short*)(ws + OFF_Sql);

  const size_t NEED_KS = 44433408;
  if (ws_size < NEED_KS) return;  // proven available in prior rounds

  float* G1 = (float*)ws;  // aliases Pw slots 0..15 (dead once K built)

  // fp32 squares: S[0]=dA^64 (Pw slot 63); S[1..5] in Pw slots 56..60
  float* S[6];
  S[0] = Pw + (size_t)63 * 65536;
  for (int d = 1; d <= 5; ++d) S[d] = Pw + (size_t)(55 + d) * 65536;

  prep0<<<129, 256, 0, stream>>>(u, dA, dB, (float*)(ws + OFF_uT), Pw, Phi, Plo, Kf, Khi, Klo);
  for (int half = 1; half <= 32; half <<= 1)
    pow_K<<<20 * half, 256, 0, stream>>>(Pw, Phi, Plo, Kf, Khi, Klo, half);

  // finals + sq0 (M^2) folded
  finals_sq<<<dim3(65, 64), 256, 0, stream>>>(Kf, u, G0, S[0], S[1], Sqh, Sql);

  const unsigned short* Mh0 = Phi + (size_t)63 * 65536;
  const unsigned short* Ml0 = Plo + (size_t)63 * 65536;
  // ks L0 (+sq1: M^4), L1 (+sq2: M^8), L2 (+sq3: M^16), L3 (+sq4: M^32), L4, L5(final)
  ks_level<0><<<272, 256, 0, stream>>>(G0, G1, Mh0, Ml0, 64, nullptr, nullptr,
                                       S[1], S[2], Sqh + 1 * 65536, Sql + 1 * 65536);
  ks_level<0><<<272, 256, 0, stream>>>(G1, G0, Sqh + 0 * 65536, Sql + 0 * 65536, 128, nullptr, nullptr,
                                       S[2], S[3], Sqh + 2 * 65536, Sql + 2 * 65536);
  ks_level<0><<<272, 256, 0, stream>>>(G0, G1, Sqh + 1 * 65536, Sql + 1 * 65536, 256, nullptr, nullptr,
                                       S[3], S[4], Sqh + 3 * 65536, Sql + 3 * 65536);
  ks_level<0><<<272, 256, 0, stream>>>(G1, G0, Sqh + 2 * 65536, Sql + 2 * 65536, 512, nullptr, nullptr,
                                       S[4], S[5], Sqh + 4 * 65536, Sql + 4 * 65536);
  ks_level<0><<<256, 256, 0, stream>>>(G0, G1, Sqh + 3 * 65536, Sql + 3 * 65536, 1024, nullptr, nullptr,
                                       nullptr, nullptr, nullptr, nullptr);
  ks_level<1><<<256, 256, 0, stream>>>(G1, nullptr, Sqh + 4 * 65536, Sql + 4 * 65536, 2048, shi, slo,
                                       nullptr, nullptr, nullptr, nullptr);

  main_gemm<<<dim3(64, 64), 256, 0, stream>>>(shi, slo, Phi, Plo, Khi, Klo,
                                              (const float*)(ws + OFF_uT), out);
}

// Round 16
// 331.915 us; speedup vs baseline: 1.1344x; 1.0000x over previous
//
#include <hip/hip_runtime.h>
#include <hip/hip_bf16.h>
#include <stdint.h>

// HiPPO-LegT LTI scan: c_t = dA c_{t-1} + dB u_t, out = all c_t. N=256, L=4096, B=64.
//   c[k*64+dt] = dA^{dt+1} . s_k  +  sum_{p<=dt} (dA^p dB) . u[k*64+dt-p]   (main_gemm, MFMA)
//   s_k via Kogge-Stone over chunk finals (6 MFMA GEMM levels, 64x64 tiles, full chip).
// All fp32 data; MFMA operands split bf16 hi/lo (3-MFMA products, rel err ~2^-17).
// FINAL CONFIGURATION (round-9 structure, reproduced twice at ~332us):
//  r7: sq_mm folded as rider blocks into finals/ks launches.
//  r8: register prefetch in mm64_tile/ks_tile + K-doubling riders in pow launches.
//  r9: main_gemm carry-phase register prefetch one kt ahead (177->165us).
// Falsified levers (kept out): LDS swizzle (r4), coop grid.sync (r5), 2-dt tiles (r6),
// stride-36 (r10, neutral), A-from-L2 (r11), single-barrier dbuf (r12),
// XCD dt-pinning (r13), setprio (r14).

#define N 256
#define LSEQ 4096
#define BATCH 64
#define TCH 64
#define NCH 64

using bf16x8 = __attribute__((ext_vector_type(8))) __bf16;
using f32x4  = __attribute__((ext_vector_type(4))) float;

__device__ __forceinline__ unsigned short f2bf(float f) {
  uint32_t x = __builtin_bit_cast(uint32_t, f);
  uint32_t r = x + 0x7fffu + ((x >> 16) & 1u);
  return (unsigned short)(r >> 16);
}
__device__ __forceinline__ float bf2f(unsigned short h) {
  uint32_t x = ((uint32_t)h) << 16;
  return __builtin_bit_cast(float, x);
}

__device__ __forceinline__ int swz(int r, int c) { return r * 32 + ((c ^ ((r >> 1) & 3)) << 3); }

// ws offsets (bytes)
#define OFF_Phi 16777216
#define OFF_Plo 25165824
#define OFF_Kf  33554432
#define OFF_Khi 33619968
#define OFF_Klo 33652736
#define OFF_shi 33685504
#define OFF_slo 35782656
#define OFF_G0  37879808
#define OFF_uT  42074112
#define OFF_Sqh 43122688
#define OFF_Sql 43778048

// ---------- device phase bodies ----------

// 64x64 fp32 GEMM tile with k0-prefetch: C = A @ B, fp32 C + bf16 hi/lo split.
__device__ __forceinline__ void mm64_tile(const float* __restrict__ A, const float* __restrict__ B,
                                          float* __restrict__ Cw, unsigned short* __restrict__ Chi,
                                          unsigned short* __restrict__ Clo, int bx, int tid,
                                          char* smem) {
  float (*At)[68] = (float(*)[68])smem;
  float (*Bs)[68] = (float(*)[68])(smem + 4352);
  int gr0 = (bx >> 2) * 64, gc0 = (bx & 3) * 64;
  int ty = tid >> 4, tx = tid & 15;
  float acc[4][4];
  #pragma unroll
  for (int r = 0; r < 4; ++r)
    #pragma unroll
    for (int c = 0; c < 4; ++c) acc[r][c] = 0.f;
  int ra = tid >> 2, ka4 = (tid & 3) << 2;
  int kb = tid >> 4, cb4 = (tid & 15) << 2;
  const float* pa = &A[(size_t)(gr0 + ra) * 256 + ka4];
  const float* pb = &B[(size_t)kb * 256 + gc0 + cb4];
  float4 va = *(const float4*)pa;
  float4 vb = *(const float4*)pb;
  for (int k0 = 0; k0 < 256; k0 += 16) {
    At[ka4 + 0][ra] = va.x; At[ka4 + 1][ra] = va.y;
    At[ka4 + 2][ra] = va.z; At[ka4 + 3][ra] = va.w;
    *(float4*)&Bs[kb][cb4] = vb;
    __syncthreads();
    if (k0 + 16 < 256) {
      va = *(const float4*)(pa + k0 + 16);
      vb = *(const float4*)(pb + (size_t)(k0 + 16) * 256);
    }
    #pragma unroll
    for (int kk = 0; kk < 16; ++kk) {
      float4 a4 = *(const float4*)&At[kk][ty << 2];
      float4 b4 = *(const float4*)&Bs[kk][tx << 2];
      acc[0][0] += a4.x * b4.x; acc[0][1] += a4.x * b4.y; acc[0][2] += a4.x * b4.z; acc[0][3] += a4.x * b4.w;
      acc[1][0] += a4.y * b4.x; acc[1][1] += a4.y * b4.y; acc[1][2] += a4.y * b4.z; acc[1][3] += a4.y * b4.w;
      acc[2][0] += a4.z * b4.x; acc[2][1] += a4.z * b4.y; acc[2][2] += a4.z * b4.z; acc[2][3] += a4.z * b4.w;
      acc[3][0] += a4.w * b4.x; acc[3][1] += a4.w * b4.y; acc[3][2] += a4.w * b4.z; acc[3][3] += a4.w * b4.w;
    }
    __syncthreads();
  }
  #pragma unroll
  for (int r = 0; r < 4; ++r)
    #pragma unroll
    for (int c = 0; c < 4; ++c) {
      size_t idx = (size_t)(gr0 + ty * 4 + r) * 256 + gc0 + tx * 4 + c;
      float v = acc[r][c];
      Cw[idx] = v;
      unsigned short h = f2bf(v);
      Chi[idx] = h;
      Clo[idx] = f2bf(v - bf2f(h));
    }
}

__device__ __forceinline__ void finals_one(const float* __restrict__ Kf, const float* __restrict__ u,
                                           float* __restrict__ G0, int k, int b, int i) {
  float acc = 0.f;
  int ubase = (k * TCH + 63) * BATCH + b;
  #pragma unroll 8
  for (int p = 0; p < TCH; ++p)
    acc += Kf[p * N + i] * u[ubase - p * BATCH];
  G0[(size_t)(k * BATCH + b) * N + i] = acc;
}

// one Kogge-Stone 64x64 tile with kt-prefetch: Gout[m] = Gin[m] + Gin[m-shift] @ M^T.
template <int FINAL>
__device__ __forceinline__ void ks_tile(int bx, int tid, const float* __restrict__ Gin,
                                        float* __restrict__ Gout,
                                        const unsigned short* __restrict__ Mh,
                                        const unsigned short* __restrict__ Ml, int shift,
                                        unsigned short* __restrict__ shi,
                                        unsigned short* __restrict__ slo, char* smem) {
  unsigned short* Ah = (unsigned short*)smem;
  unsigned short* Al = (unsigned short*)(smem + 4096);
  unsigned short* Bh = (unsigned short*)(smem + 8192);
  unsigned short* Bl = (unsigned short*)(smem + 12288);
  int kb0 = (bx >> 2) * 64, i0 = (bx & 3) * 64;
  int lane = tid & 63, wid = tid >> 6;
  int wr = wid >> 1, wc = wid & 1;
  int rg = lane >> 4, cl = lane & 15;

  f32x4 acc[2][2];
  #pragma unroll
  for (int mf = 0; mf < 2; ++mf) {
    int m0 = kb0 + wr * 32 + mf * 16 + rg * 4;
    #pragma unroll
    for (int nf = 0; nf < 2; ++nf) {
      int i = i0 + wc * 32 + nf * 16 + cl;
      #pragma unroll
      for (int r = 0; r < 4; ++r)
        acc[mf][nf][r] = Gin[(size_t)(m0 + r) * 256 + i];
    }
  }

  int sr = tid >> 2, kc = tid & 3;
  int sw = swz(sr, kc);
  int srow = kb0 + sr - shift;
  bool haveA = (srow >= 0);
  const float* srcA = &Gin[(size_t)(haveA ? srow : 0) * 256 + kc * 8];
  const unsigned short* srcBh = &Mh[(size_t)(i0 + sr) * 256 + kc * 8];
  const unsigned short* srcBl = &Ml[(size_t)(i0 + sr) * 256 + kc * 8];

  float4 rA0, rA1;
  uint4 rBh = *(const uint4*)srcBh, rBl = *(const uint4*)srcBl;
  if (haveA) { rA0 = *(const float4*)srcA; rA1 = *(const float4*)(srcA + 4); }

  for (int kt = 0; kt < 8; ++kt) {
    if (haveA) {
      float vv[8] = {rA0.x, rA0.y, rA0.z, rA0.w, rA1.x, rA1.y, rA1.z, rA1.w};
      unsigned short hv[8], lv[8];
      #pragma unroll
      for (int e = 0; e < 8; ++e) {
        hv[e] = f2bf(vv[e]);
        lv[e] = f2bf(vv[e] - bf2f(hv[e]));
      }
      *(uint4*)&Ah[sw] = *(const uint4*)hv;
      *(uint4*)&Al[sw] = *(const uint4*)lv;
    } else {
      uint4 z = {0, 0, 0, 0};
      *(uint4*)&Ah[sw] = z;
      *(uint4*)&Al[sw] = z;
    }
    *(uint4*)&Bh[sw] = rBh;
    *(uint4*)&Bl[sw] = rBl;
    __syncthreads();

    if (kt < 7) {
      int off = (kt + 1) * 32;
      if (haveA) { rA0 = *(const float4*)(srcA + off); rA1 = *(const float4*)(srcA + off + 4); }
      rBh = *(const uint4*)(srcBh + off);
      rBl = *(const uint4*)(srcBl + off);
    }

    int fr = lane & 15, kseg = lane >> 4;
    bf16x8 ah[2], al[2], bh[2], bl[2];
    #pragma unroll
    for (int mf = 0; mf < 2; ++mf) {
      int row = wr * 32 + mf * 16 + fr;
      ah[mf] = *(const bf16x8*)&Ah[swz(row, kseg)];
      al[mf] = *(const bf16x8*)&Al[swz(row, kseg)];
    }
    #pragma unroll
    for (int nf = 0; nf < 2; ++nf) {
      int row = wc * 32 + nf * 16 + fr;
      bh[nf] = *(const bf16x8*)&Bh[swz(row, kseg)];
      bl[nf] = *(const bf16x8*)&Bl[swz(row, kseg)];
    }
    #pragma unroll
    for (int mf = 0; mf < 2; ++mf)
      #pragma unroll
      for (int nf = 0; nf < 2; ++nf) {
        acc[mf][nf] = __builtin_amdgcn_mfma_f32_16x16x32_bf16(ah[mf], bh[nf], acc[mf][nf], 0, 0, 0);
        acc[mf][nf] = __builtin_amdgcn_mfma_f32_16x16x32_bf16(ah[mf], bl[nf], acc[mf][nf], 0, 0, 0);
        acc[mf][nf] = __builtin_amdgcn_mfma_f32_16x16x32_bf16(al[mf], bh[nf], acc[mf][nf], 0, 0, 0);
      }
    __syncthreads();
  }

  #pragma unroll
  for (int mf = 0; mf < 2; ++mf) {
    int m0 = kb0 + wr * 32 + mf * 16 + rg * 4;
    #pragma unroll
    for (int nf = 0; nf < 2; ++nf) {
      int i = i0 + wc * 32 + nf * 16 + cl;
      #pragma unroll
      for (int r = 0; r < 4; ++r) {
        if (FINAL) {
          int tm = m0 + r + 64;
          if (tm < 4096) {
            float v = acc[mf][nf][r];
            unsigned short h = f2bf(v);
            shi[(size_t)tm * 256 + i] = h;
            slo[(size_t)tm * 256 + i] = f2bf(v - bf2f(h));
          }
        } else {
          Gout[(size_t)(m0 + r) * 256 + i] = acc[mf][nf][r];
        }
      }
    }
  }
  if (FINAL && kb0 == 0) {
    for (int e = tid; e < 4096; e += 256) {
      size_t o = (size_t)(e >> 6) * 256 + i0 + (e & 63);
      shi[o] = 0;
      slo[o] = 0;
    }
  }
}

// ---------- standalone kernels ----------

// prep0: bid<64 transpose u; bid<128 dA copy/split; bid==128 K[0]=dB init.
__global__ __launch_bounds__(256) void prep0(const float* __restrict__ u, const float* __restrict__ dA,
                                             const float* __restrict__ dB,
                                             float* __restrict__ uT, float* __restrict__ Pw,
                                             unsigned short* __restrict__ Phi, unsigned short* __restrict__ Plo,
                                             float* __restrict__ Kf, unsigned short* __restrict__ Khi,
                                             unsigned short* __restrict__ Klo) {
  __shared__ float tile[64][65];
  int bid = blockIdx.x, tid = threadIdx.x;
  if (bid < 64) {
    int t0 = bid * 64;
    #pragma unroll
    for (int q = 0; q < 16; ++q) {
      int e = q * 256 + tid;
      int tt = e >> 6, b = e & 63;
      tile[b][tt] = u[(size_t)(t0 + tt) * 64 + b];
    }
    __syncthreads();
    #pragma unroll
    for (int q = 0; q < 16; ++q) {
      int e = q * 256 + tid;
      int b = e >> 6, tt = e & 63;
      uT[(size_t)b * 4096 + t0 + tt] = tile[b][tt];
    }
  } else if (bid < 128) {
    int base = (bid - 64) * 1024 + tid * 4;
    float4 v = *(const float4*)&dA[base];
    *(float4*)&Pw[base] = v;
    float vv[4] = {v.x, v.y, v.z, v.w};
    #pragma unroll
    for (int q = 0; q < 4; ++q) {
      unsigned short h = f2bf(vv[q]);
      Phi[base + q] = h;
      Plo[base + q] = f2bf(vv[q] - bf2f(h));
    }
  } else {
    float v = dB[tid];
    Kf[tid] = v;
    unsigned short h = f2bf(v);
    Khi[tid] = h;
    Klo[tid] = f2bf(v - bf2f(h));
  }
}

// pow_K: level half. Blocks [0,16*half): P[half+q] = P[q] @ P[half] (fp32 + split).
// Blocks [16*half, 20*half): K-riders, K[half+j] = P[half] . K[j] (wave row-dots).
__global__ __launch_bounds__(256) void pow_K(float* __restrict__ Pw,
                                             unsigned short* __restrict__ Phi,
                                             unsigned short* __restrict__ Plo,
                                             float* __restrict__ Kf,
                                             unsigned short* __restrict__ Khi,
                                             unsigned short* __restrict__ Klo,
                                             int half) {
  __shared__ __align__(16) char smem[16640];
  int bx = blockIdx.x, tid = threadIdx.x;
  if (bx < 16 * half) {
    int q = (bx >> 4) + 1, t = bx & 15;
    mm64_tile(Pw + (size_t)(q - 1) * 65536, Pw + (size_t)(half - 1) * 65536,
              Pw + (size_t)(half + q - 1) * 65536, Phi + (size_t)(half + q - 1) * 65536,
              Plo + (size_t)(half + q - 1) * 65536, t, tid, smem);
  } else {
    int r = bx - 16 * half;
    int jp = r >> 2, quarter = r & 3;
    int p = half + jp;
    const float* M = Pw + (size_t)(half - 1) * 65536;
    const float* v = Kf + (size_t)jp * 256;
    int lane = tid & 63, w = tid >> 6;
    float d0 = v[lane], d1 = v[lane + 64], d2 = v[lane + 128], d3 = v[lane + 192];
    for (int ii = 0; ii < 16; ++ii) {
      int i = quarter * 64 + w * 16 + ii;
      const float* row = M + (size_t)i * 256;
      float acc = row[lane] * d0 + row[lane + 64] * d1 + row[lane + 128] * d2 + row[lane + 192] * d3;
      #pragma unroll
      for (int off = 32; off; off >>= 1) acc += __shfl_xor(acc, off, 64);
      if (lane == 0) {
        Kf[p * 256 + i] = acc;
        unsigned short h = f2bf(acc);
        Khi[p * 256 + i] = h;
        Klo[p * 256 + i] = f2bf(acc - bf2f(h));
      }
    }
  }
}

// finals (grid 65 x 64) + folded sq0.
__global__ __launch_bounds__(256) void finals_sq(const float* __restrict__ Kf, const float* __restrict__ u,
                                                 float* __restrict__ G0,
                                                 const float* __restrict__ S0, float* __restrict__ S1,
                                                 unsigned short* __restrict__ Sqh0,
                                                 unsigned short* __restrict__ Sql0) {
  __shared__ __align__(16) char smem[16640];
  if (blockIdx.x < 64) {
    finals_one(Kf, u, G0, blockIdx.x, blockIdx.y, threadIdx.x);
  } else if (blockIdx.y < 16) {
    mm64_tile(S0, S0, S1, Sqh0, Sql0, blockIdx.y, threadIdx.x, smem);
  }
}

// ks_level + optional folded square: blocks >=256 compute SqC = SqA @ SqA (16 tiles).
template <int FINAL>
__global__ __launch_bounds__(256) void ks_level(const float* __restrict__ Gin, float* __restrict__ Gout,
                                                const unsigned short* __restrict__ Mh,
                                                const unsigned short* __restrict__ Ml, int shift,
                                                unsigned short* __restrict__ shi,
                                                unsigned short* __restrict__ slo,
                                                const float* __restrict__ SqA, float* __restrict__ SqC,
                                                unsigned short* __restrict__ SqChi,
                                                unsigned short* __restrict__ SqClo) {
  __shared__ __align__(16) char smem[16640];
  int bx = blockIdx.x;
  if (bx < 256) {
    ks_tile<FINAL>(bx, threadIdx.x, Gin, Gout, Mh, Ml, shift, shi, slo, smem);
  } else {
    mm64_tile(SqA, SqA, SqC, SqChi, SqClo, bx - 256, threadIdx.x, smem);
  }
}

// main_gemm: out[k*64+dt][b][i] = sum_j P[dt+1][i][j] s_k[b][j] + sum_{p<=dt} K[p][i] u[kT+dt-p][b]
// r9 proven version: stride-40 LDS, 2-barrier, carry-phase register prefetch one kt ahead.
__global__ __launch_bounds__(256, 2) void main_gemm(const unsigned short* __restrict__ shi,
                                                    const unsigned short* __restrict__ slo,
                                                    const unsigned short* __restrict__ Phi,
                                                    const unsigned short* __restrict__ Plo,
                                                    const unsigned short* __restrict__ Khi,
                                                    const unsigned short* __restrict__ Klo,
                                                    const float* __restrict__ uT,
                                                    float* __restrict__ out) {
  __shared__ unsigned short Ah[128 * 40], Al[128 * 40], Bh[128 * 40], Bl[128 * 40];
  int dt = blockIdx.y;
  int x = blockIdx.x;
  int it = x >> 5, kbt = x & 31;
  int kb0 = kbt * 128, i0 = it * 128;
  int tid = threadIdx.x;
  int lane = tid & 63, wid = tid >> 6;
  int wr = wid >> 1, wc = wid & 1;

  f32x4 acc[4][4];
  #pragma unroll
  for (int mf = 0; mf < 4; ++mf)
    #pragma unroll
    for (int nf = 0; nf < 4; ++nf)
      #pragma unroll
      for (int r = 0; r < 4; ++r) acc[mf][nf][r] = 0.f;

  const unsigned short* PhiD = Phi + (size_t)dt * 65536;
  const unsigned short* PloD = Plo + (size_t)dt * 65536;
  int nkt = (dt >= 32) ? 10 : 9;

  // carry-phase staging bases (loop-invariant); prefetch regs hold kt's 8 uint4
  int r = tid >> 1, h = tid & 1;
  int lo_ = r * 40 + h * 16;
  const unsigned short* b1 = shi  + (size_t)(kb0 + r) * 256 + h * 16;
  const unsigned short* b2 = slo  + (size_t)(kb0 + r) * 256 + h * 16;
  const unsigned short* b3 = PhiD + (size_t)(i0 + r) * 256 + h * 16;
  const unsigned short* b4 = PloD + (size_t)(i0 + r) * 256 + h * 16;
  uint4 r1a = *(const uint4*)b1;
  uint4 r1b = *(const uint4*)(b1 + 8);
  uint4 r2a = *(const uint4*)b2;
  uint4 r2b = *(const uint4*)(b2 + 8);
  uint4 r3a = *(const uint4*)b3;
  uint4 r3b = *(const uint4*)(b3 + 8);
  uint4 r4a = *(const uint4*)b4;
  uint4 r4b = *(const uint4*)(b4 + 8);

  for (int kt = 0; kt < nkt; ++kt) {
    if (kt < 8) {
      *(uint4*)&Ah[lo_]     = r1a;
      *(uint4*)&Ah[lo_ + 8] = r1b;
      *(uint4*)&Al[lo_]     = r2a;
      *(uint4*)&Al[lo_ + 8] = r2b;
      *(uint4*)&Bh[lo_]     = r3a;
      *(uint4*)&Bh[lo_ + 8] = r3b;
      *(uint4*)&Bl[lo_]     = r4a;
      *(uint4*)&Bl[lo_ + 8] = r4b;
    } else {
      int p0 = (kt - 8) * 32;
      int kk = (kb0 + r) >> 6, b = (kb0 + r) & 63;
      const float* ub2 = uT + (size_t)b * 4096 + kk * 64 + dt;
      #pragma unroll
      for (int qq = 0; qq < 16; ++qq) {
        int pp = h * 16 + qq;
        int sh = p0 + pp;
        float v = (sh <= dt) ? ub2[-sh] : 0.f;
        unsigned short hv = f2bf(v);
        Ah[r * 40 + pp] = hv;
        Al[r * 40 + pp] = f2bf(v - bf2f(hv));
      }
      int n = tid & 127, ph = tid >> 7;
      #pragma unroll
      for (int qq = 0; qq < 16; ++qq) {
        int pp = ph * 16 + qq;
        Bh[n * 40 + pp] = Khi[(p0 + pp) * 256 + i0 + n];
        Bl[n * 40 + pp] = Klo[(p0 + pp) * 256 + i0 + n];
      }
    }
    __syncthreads();

    // issue next carry-phase loads early: latency hides under this kt's MFMAs
    if (kt + 1 < 8) {
      int co = (kt + 1) * 32;
      r1a = *(const uint4*)(b1 + co);
      r1b = *(const uint4*)(b1 + co + 8);
      r2a = *(const uint4*)(b2 + co);
      r2b = *(const uint4*)(b2 + co + 8);
      r3a = *(const uint4*)(b3 + co);
      r3b = *(const uint4*)(b3 + co + 8);
      r4a = *(const uint4*)(b4 + co);
      r4b = *(const uint4*)(b4 + co + 8);
    }

    int kseg = lane >> 4, fr = lane & 15;
    bf16x8 ah[4], al[4], bh[4], bl[4];
    #pragma unroll
    for (int mf = 0; mf < 4; ++mf) {
      int row = (wr * 64 + mf * 16 + fr) * 40 + kseg * 8;
      ah[mf] = *(const bf16x8*)&Ah[row];
      al[mf] = *(const bf16x8*)&Al[row];
    }
    #pragma unroll
    for (int nf = 0; nf < 4; ++nf) {
      int row = (wc * 64 + nf * 16 + fr) * 40 + kseg * 8;
      bh[nf] = *(const bf16x8*)&Bh[row];
      bl[nf] = *(const bf16x8*)&Bl[row];
    }
    #pragma unroll
    for (int mf = 0; mf < 4; ++mf)
      #pragma unroll
      for (int nf = 0; nf < 4; ++nf) {
        acc[mf][nf] = __builtin_amdgcn_mfma_f32_16x16x32_bf16(ah[mf], bh[nf], acc[mf][nf], 0, 0, 0);
        acc[mf][nf] = __builtin_amdgcn_mfma_f32_16x16x32_bf16(ah[mf], bl[nf], acc[mf][nf], 0, 0, 0);
        acc[mf][nf] = __builtin_amdgcn_mfma_f32_16x16x32_bf16(al[mf], bh[nf], acc[mf][nf], 0, 0, 0);
      }
    __syncthreads();
  }

  int rg = lane >> 4, cl = lane & 15;
  #pragma unroll
  for (int mf = 0; mf < 4; ++mf) {
    int kbrow_base = kb0 + wr * 64 + mf * 16 + rg * 4;
    #pragma unroll
    for (int nf = 0; nf < 4; ++nf) {
      int i = i0 + wc * 64 + nf * 16 + cl;
      #pragma unroll
      for (int rr = 0; rr < 4; ++rr) {
        int kbrow = kbrow_base + rr;
        int k = kbrow >> 6, b = kbrow & 63;
        size_t t = (size_t)(k * 64 + dt);
        out[(t * 64 + b) * 256 + i] = acc[mf][nf][rr];
      }
    }
  }
}

// ======================= HOST =======================

extern "C" void kernel_launch(void* const* d_in, const int* in_sizes, int n_in,
                              void* d_out, int out_size, void* d_ws, size_t ws_size,
                              hipStream_t stream) {
  (void)in_sizes; (void)n_in; (void)out_size;
  const float* u  = (const float*)d_in[0];
  const float* dA = (const float*)d_in[1];
  const float* dB = (const float*)d_in[2];
  float* out = (float*)d_out;
  char* ws = (char*)d_ws;

  float*          Pw  = (float*)(ws);
  unsigned short* Phi = (unsigned short*)(ws + OFF_Phi);
  unsigned short* Plo = (unsigned short*)(ws + OFF_Plo);
  float*          Kf  = (float*)(ws + OFF_Kf);
  unsigned short* Khi = (unsigned short*)(ws + OFF_Khi);
  unsigned short* Klo = (unsigned short*)(ws + OFF_Klo);
  unsigned short* shi = (unsigned short*)(ws + OFF_shi);
  unsigned short* slo = (unsigned short*)(ws + OFF_slo);
  float*          G0  = (float*)(ws + OFF_G0);
  unsigned short* Sqh = (unsigned short*)(ws + OFF_Sqh);
  unsigned short* Sql = (unsigned short*)(ws + OFF_Sql);

  const size_t NEED_KS = 44433408;
  if (ws_size < NEED_KS) return;  // proven available in prior rounds

  float* G1 = (float*)ws;  // aliases Pw slots 0..15 (dead once K built)

  // fp32 squares: S[0]=dA^64 (Pw slot 63); S[1..5] in Pw slots 56..60
  float* S[6];
  S[0] = Pw + (size_t)63 * 65536;
  for (int d = 1; d <= 5; ++d) S[d] = Pw + (size_t)(55 + d) * 65536;

  prep0<<<129, 256, 0, stream>>>(u, dA, dB, (float*)(ws + OFF_uT), Pw, Phi, Plo, Kf, Khi, Klo);
  for (int half = 1; half <= 32; half <<= 1)
    pow_K<<<20 * half, 256, 0, stream>>>(Pw, Phi, Plo, Kf, Khi, Klo, half);

  // finals + sq0 (M^2) folded
  finals_sq<<<dim3(65, 64), 256, 0, stream>>>(Kf, u, G0, S[0], S[1], Sqh, Sql);

  const unsigned short* Mh0 = Phi + (size_t)63 * 65536;
  const unsigned short* Ml0 = Plo + (size_t)63 * 65536;
  // ks L0 (+sq1: M^4), L1 (+sq2: M^8), L2 (+sq3: M^16), L3 (+sq4: M^32), L4, L5(final)
  ks_level<0><<<272, 256, 0, stream>>>(G0, G1, Mh0, Ml0, 64, nullptr, nullptr,
                                       S[1], S[2], Sqh + 1 * 65536, Sql + 1 * 65536);
  ks_level<0><<<272, 256, 0, stream>>>(G1, G0, Sqh + 0 * 65536, Sql + 0 * 65536, 128, nullptr, nullptr,
                                       S[2], S[3], Sqh + 2 * 65536, Sql + 2 * 65536);
  ks_level<0><<<272, 256, 0, stream>>>(G0, G1, Sqh + 1 * 65536, Sql + 1 * 65536, 256, nullptr, nullptr,
                                       S[3], S[4], Sqh + 3 * 65536, Sql + 3 * 65536);
  ks_level<0><<<272, 256, 0, stream>>>(G1, G0, Sqh + 2 * 65536, Sql + 2 * 65536, 512, nullptr, nullptr,
                                       S[4], S[5], Sqh + 4 * 65536, Sql + 4 * 65536);
  ks_level<0><<<256, 256, 0, stream>>>(G0, G1, Sqh + 3 * 65536, Sql + 3 * 65536, 1024, nullptr, nullptr,
                                       nullptr, nullptr, nullptr, nullptr);
  ks_level<1><<<256, 256, 0, stream>>>(G1, nullptr, Sqh + 4 * 65536, Sql + 4 * 65536, 2048, shi, slo,
                                       nullptr, nullptr, nullptr, nullptr);

  main_gemm<<<dim3(64, 64), 256, 0, stream>>>(shi, slo, Phi, Plo, Khi, Klo,
                                              (const float*)(ws + OFF_uT), out);
}